// Round 6
// baseline (449.976 us; speedup 1.0000x reference)
//
#include <hip/hip_runtime.h>
#include <hip/hip_bf16.h>
#include <cstddef>

#define NN 50000
#define EE 800000
#define TE 850000   // EE + NN self loops
#define INC 256
#define C1 128      // heads(2) * hid(64)
#define C2 64
#define NCHUNK 49   // ceil(NN/1024)

typedef unsigned short ushort_t;
typedef short bf16x8 __attribute__((ext_vector_type(8)));
typedef float f32x4 __attribute__((ext_vector_type(4)));

__device__ inline ushort_t bf16r(float f) {  // RNE float->bf16
    unsigned u = __float_as_uint(f);
    unsigned r = (u + 0x7fffu + ((u >> 16) & 1u)) >> 16;
    return (ushort_t)r;
}
#define BF2F(u) (__uint_as_float(((unsigned)(u)) << 16))
#define LOF(u) (__uint_as_float((u) << 16))           // low bf16 of packed uint
#define HIF(u) (__uint_as_float((u) & 0xffff0000u))   // high bf16 of packed uint

// ---------------- CSR build ----------------

__global__ void k_zero(int* p, int n) {
    int i = blockIdx.x * blockDim.x + threadIdx.x;
    if (i < n) p[i] = 0;
}

__global__ void k_count(const int* __restrict__ ei, int* __restrict__ deg) {
    int e = blockIdx.x * blockDim.x + threadIdx.x;
    if (e >= TE) return;
    int dst = (e < EE) ? ei[EE + e] : (e - EE);
    atomicAdd(&deg[dst], 1);
}

__global__ void k_scan1(const int* __restrict__ deg, int* __restrict__ incl,
                        int* __restrict__ totals) {
    __shared__ int lds[1024];
    int t = threadIdx.x;
    int i = blockIdx.x * 1024 + t;
    int v = (i < NN) ? deg[i] : 0;
    lds[t] = v;
    __syncthreads();
    for (int off = 1; off < 1024; off <<= 1) {
        int add = (t >= off) ? lds[t - off] : 0;
        __syncthreads();
        lds[t] += add;
        __syncthreads();
    }
    if (i < NN) incl[i] = lds[t];
    if (t == 1023) totals[blockIdx.x] = lds[t];
}

__global__ void k_scan2(const int* __restrict__ totals, int* __restrict__ chunkoff) {
    int t = threadIdx.x;
    int orig = (t < NCHUNK) ? totals[t] : 0;
    int v = orig;
    for (int off = 1; off < 64; off <<= 1) {
        int u = __shfl_up(v, off, 64);
        if (t >= off) v += u;
    }
    if (t < NCHUNK) chunkoff[t] = v - orig;
}

__global__ void k_scan3(const int* __restrict__ incl, const int* __restrict__ deg,
                        const int* __restrict__ chunkoff, int* __restrict__ rowstart,
                        int* __restrict__ writeptr) {
    int i = blockIdx.x * blockDim.x + threadIdx.x;
    if (i == 0) rowstart[NN] = TE;
    if (i >= NN) return;
    int rs = incl[i] - deg[i] + chunkoff[i >> 10];
    rowstart[i] = rs;
    writeptr[i] = rs;
}

// atomic-only position pass: NO random store (posarr is coalesced by e)
__global__ void k_pos(const int* __restrict__ ei, int* __restrict__ writeptr,
                      int* __restrict__ posarr) {
    int e = blockIdx.x * blockDim.x + threadIdx.x;
    if (e >= TE) return;
    int d = (e < EE) ? ei[EE + e] : (e - EE);
    posarr[e] = atomicAdd(&writeptr[d], 1);
}

// ---------------- casts / weight prep ----------------

__global__ void k_cast4(const float* __restrict__ src, ushort_t* __restrict__ dst, int n4) {
    int i = blockIdx.x * blockDim.x + threadIdx.x;
    if (i >= n4) return;
    float4 a = ((const float4*)src)[i];
    ushort4 o;
    o.x = bf16r(a.x); o.y = bf16r(a.y); o.z = bf16r(a.z); o.w = bf16r(a.w);
    ((ushort4*)dst)[i] = o;
}

__global__ void k_prep_w(const float* __restrict__ Wl, const float* __restrict__ Wr,
                         const float* __restrict__ bl, const float* __restrict__ br,
                         ushort_t* __restrict__ Wt, float* __restrict__ biasf,
                         int K, int HALF) {
    int n = blockIdx.x;
    int k = threadIdx.x;
    const float* W = (n < HALF) ? Wl : Wr;
    int c = (n < HALF) ? n : n - HALF;
    Wt[(size_t)n * K + k] = bf16r(W[(size_t)k * HALF + c]);
    if (n == 0 && k < 2 * HALF) biasf[k] = (k < HALF) ? bl[k] : br[k - HALF];
}

// ---------------- bf16 MFMA GEMM ----------------
// C[M,NCOL](bf16) = A[M,K](bf16) @ Bt[NCOL,K]^T + bias(fp32)
// 128x128 tile, BK=32, 256 threads, 16x16x32 MFMA; LDS rows padded to 40 bf16.

template <int K, int NCOL>
__global__ __launch_bounds__(256) void k_gemm_mfma(const ushort_t* __restrict__ A,
                                                   const ushort_t* __restrict__ Bt,
                                                   const float* __restrict__ bias,
                                                   ushort_t* __restrict__ C, int M) {
    __shared__ __align__(16) ushort_t As[128 * 40];
    __shared__ __align__(16) ushort_t Bs[128 * 40];
    int tid = threadIdx.x;
    int bm = blockIdx.x * 128;
    int bn = blockIdx.y * 128;
    int w = tid >> 6, l = tid & 63;
    int wm = (w & 1) * 64, wn = (w >> 1) * 64;
    int lm = l & 15, half = l >> 4;

    f32x4 zero = {0.f, 0.f, 0.f, 0.f};
    f32x4 acc[4][4];
#pragma unroll
    for (int a = 0; a < 4; a++)
#pragma unroll
        for (int b = 0; b < 4; b++) acc[a][b] = zero;

    for (int k0 = 0; k0 < K; k0 += 32) {
#pragma unroll
        for (int q = 0; q < 2; q++) {
            int seg = q * 256 + tid;
            int m = seg >> 2;
            int ko = (seg & 3) * 8;
            *(float4*)&As[m * 40 + ko] = *(const float4*)&A[(size_t)(bm + m) * K + k0 + ko];
            *(float4*)&Bs[m * 40 + ko] = *(const float4*)&Bt[(size_t)(bn + m) * K + k0 + ko];
        }
        __syncthreads();
        bf16x8 af[4], bfr[4];
#pragma unroll
        for (int mi = 0; mi < 4; mi++)
            af[mi] = *(const bf16x8*)&As[(wm + mi * 16 + lm) * 40 + half * 8];
#pragma unroll
        for (int ni = 0; ni < 4; ni++)
            bfr[ni] = *(const bf16x8*)&Bs[(wn + ni * 16 + lm) * 40 + half * 8];
#pragma unroll
        for (int mi = 0; mi < 4; mi++)
#pragma unroll
            for (int ni = 0; ni < 4; ni++)
                acc[mi][ni] = __builtin_amdgcn_mfma_f32_16x16x32_bf16(
                    af[mi], bfr[ni], acc[mi][ni], 0, 0, 0);
        __syncthreads();
    }
#pragma unroll
    for (int ni = 0; ni < 4; ni++) {
        int col = bn + wn + ni * 16 + lm;
        float bv = bias[col];
#pragma unroll
        for (int mi = 0; mi < 4; mi++) {
            int rbase = bm + wm + mi * 16 + half * 4;
#pragma unroll
            for (int r = 0; r < 4; r++) {
                int row = rbase + r;
                if (row < M) C[(size_t)row * NCOL + col] = bf16r(acc[mi][ni][r] + bv);
            }
        }
    }
}

// ---------------- Pass A: edge-parallel logits (original edge order) ----------------
// 4 lanes per edge; lane q covers chunk c = q + 4*it (8 channels each).
// Writes packed {src, p...} record to CSR slot posarr[e]  (the one random store).

__device__ inline float lrelu_dot2(unsigned ua, unsigned ub, float at_lo, float at_hi) {
    float alo = __uint_as_float(ua << 16), ahi = __uint_as_float(ua & 0xffff0000u);
    float blo = __uint_as_float(ub << 16), bhi = __uint_as_float(ub & 0xffff0000u);
    float t0 = alo + blo, t1 = ahi + bhi;
    float l0 = fmaxf(t0, 0.f) + 0.2f * fminf(t0, 0.f);
    float l1 = fmaxf(t1, 0.f) + 0.2f * fminf(t1, 0.f);
    return at_lo * l0 + at_hi * l1;
}

template <int STRIDE, int ITS, int HEADS>
__global__ __launch_bounds__(256) void k_edge(
    const ushort_t* __restrict__ xlr,
    const int* __restrict__ ei, const int* __restrict__ posarr,
    const float* __restrict__ att, float* __restrict__ spk) {
    int l = threadIdx.x & 63;
    int wv = threadIdx.x >> 6;
    int q = l & 3;
    int e = blockIdx.x * 64 + wv * 16 + (l >> 2);
    if (e >= TE) return;
    int src, dst;
    if (e < EE) { src = ei[e]; dst = ei[EE + e]; }
    else        { src = dst = e - EE; }
    const ushort_t* xl = xlr + (size_t)src * STRIDE;
    const ushort_t* xr = xlr + (size_t)dst * STRIDE + STRIDE / 2;
    float w[HEADS];
#pragma unroll
    for (int h = 0; h < HEADS; h++) w[h] = 0.f;
#pragma unroll
    for (int it = 0; it < ITS; it++) {
        int c = q + 4 * it;  // chunk of 8 channels
        uint4 a = *(const uint4*)&xl[c * 8];
        uint4 b = *(const uint4*)&xr[c * 8];
        float4 t0 = *(const float4*)&att[c * 8];
        float4 t1 = *(const float4*)&att[c * 8 + 4];
        int h = (HEADS == 2 && it >= ITS / 2) ? 1 : 0;
        float d = lrelu_dot2(a.x, b.x, t0.x, t0.y)
                + lrelu_dot2(a.y, b.y, t0.z, t0.w)
                + lrelu_dot2(a.z, b.z, t1.x, t1.y)
                + lrelu_dot2(a.w, b.w, t1.z, t1.w);
        w[h] += d;
    }
#pragma unroll
    for (int h = 0; h < HEADS; h++) {
        w[h] += __shfl_xor(w[h], 1, 64);
        w[h] += __shfl_xor(w[h], 2, 64);
    }
    if (q == 0) {
        int pos = posarr[e];
        if (HEADS == 2) {
            float4 rec = make_float4(__int_as_float(src), __expf(w[0]), __expf(w[1]), 0.f);
            ((float4*)spk)[pos] = rec;
        } else {
            float2 rec = make_float2(__int_as_float(src), __expf(w[0]));
            ((float2*)spk)[pos] = rec;
        }
    }
}

// ---------------- Pass B: node-parallel aggregation + epilogue ----------------
// Lane loads a packed uint = 2 bf16 channels; one 16B/8B broadcast per edge for {src,p}.

// Layer 1: block 128 = 2 waves, one node; wave w owns edges {row+w, row+w+2, ...}.
// Lane covers channels {2*lane, 2*lane+1}; head = lane>>5.
__global__ __launch_bounds__(128) void k_aggr1(
    const ushort_t* __restrict__ xlr, const float* __restrict__ spk,
    const int* __restrict__ rowstart,
    const float* __restrict__ bias,
    const float* __restrict__ g, const float* __restrict__ b,
    const float* __restrict__ m, const float* __restrict__ v,
    ushort_t* __restrict__ out) {
    __shared__ float comb[3][64];
    int i = blockIdx.x;
    int lane = threadIdx.x & 63;
    int wv = threadIdx.x >> 6;
    int head = lane >> 5;
    int row = rowstart[i], end = rowstart[i + 1];
    float ax = 0.f, ay = 0.f, s = 0.f;
    int j = row + wv;
    for (; j + 6 < end; j += 8) {  // 4 edges per wave per iter (stride 2)
        float4 e0 = ((const float4*)spk)[j],     e1 = ((const float4*)spk)[j + 2];
        float4 e2 = ((const float4*)spk)[j + 4], e3 = ((const float4*)spk)[j + 6];
        int s0 = __float_as_int(e0.x), s1 = __float_as_int(e1.x);
        int s2 = __float_as_int(e2.x), s3 = __float_as_int(e3.x);
        float p0 = head ? e0.z : e0.y, p1 = head ? e1.z : e1.y;
        float p2 = head ? e2.z : e2.y, p3 = head ? e3.z : e3.y;
        unsigned u0 = *(const unsigned*)&xlr[(size_t)s0 * 256 + 2 * lane];
        unsigned u1 = *(const unsigned*)&xlr[(size_t)s1 * 256 + 2 * lane];
        unsigned u2 = *(const unsigned*)&xlr[(size_t)s2 * 256 + 2 * lane];
        unsigned u3 = *(const unsigned*)&xlr[(size_t)s3 * 256 + 2 * lane];
        ax += p0 * LOF(u0) + p1 * LOF(u1) + p2 * LOF(u2) + p3 * LOF(u3);
        ay += p0 * HIF(u0) + p1 * HIF(u1) + p2 * HIF(u2) + p3 * HIF(u3);
        s += (p0 + p1) + (p2 + p3);
    }
    for (; j < end; j += 2) {
        float4 e0 = ((const float4*)spk)[j];
        int src = __float_as_int(e0.x);
        float pj = head ? e0.z : e0.y;
        unsigned u = *(const unsigned*)&xlr[(size_t)src * 256 + 2 * lane];
        ax += pj * LOF(u);
        ay += pj * HIF(u);
        s += pj;
    }
    if (wv == 1) { comb[0][lane] = ax; comb[1][lane] = ay; comb[2][lane] = s; }
    __syncthreads();
    if (wv == 0) {
        ax += comb[0][lane]; ay += comb[1][lane]; s += comb[2][lane];
        float inv = 1.f / s;
        float2 bb = ((const float2*)bias)[lane];
        float2 mm = ((const float2*)m)[lane];
        float2 vv = ((const float2*)v)[lane];
        float2 gg = ((const float2*)g)[lane];
        float2 bb2 = ((const float2*)b)[lane];
        float ox = ax * inv + bb.x, oy = ay * inv + bb.y;
        ox = (ox - mm.x) * rsqrtf(vv.x + 1e-5f) * gg.x + bb2.x;
        oy = (oy - mm.y) * rsqrtf(vv.y + 1e-5f) * gg.y + bb2.y;
        ox = (ox > 0.f) ? ox : (__expf(ox) - 1.f);
        oy = (oy > 0.f) ? oy : (__expf(oy) - 1.f);
        unsigned wpack = (unsigned)bf16r(ox) | ((unsigned)bf16r(oy) << 16);
        *(unsigned*)&out[(size_t)i * C1 + 2 * lane] = wpack;
    }
}

// Layer 2 + classifier: block 128 = 2 waves, one node; 4 edge slots (wave x half-wave).
// c2 = lane&31 covers channels {2*c2, 2*c2+1}.
__global__ __launch_bounds__(128) void k_aggr2(
    const ushort_t* __restrict__ xlr, const float* __restrict__ spk,
    const int* __restrict__ rowstart,
    const float* __restrict__ bias,
    const float* __restrict__ g, const float* __restrict__ b,
    const float* __restrict__ m, const float* __restrict__ v,
    const float* __restrict__ Wc, const float* __restrict__ bc,
    float* __restrict__ out) {
    __shared__ float comb[3][32];
    int i = blockIdx.x;
    int lane = threadIdx.x & 63;
    int wv = threadIdx.x >> 6;
    int half = lane >> 5;
    int c2 = lane & 31;
    int row = rowstart[i], end = rowstart[i + 1];
    float ax = 0.f, ay = 0.f, s = 0.f;
    int j = row + wv * 2 + half;
    for (; j + 4 < end; j += 8) {  // 2 edges per slot per iter (stride 4)
        float2 e0 = ((const float2*)spk)[j], e1 = ((const float2*)spk)[j + 4];
        int s0 = __float_as_int(e0.x), s1 = __float_as_int(e1.x);
        float p0 = e0.y, p1 = e1.y;
        unsigned u0 = *(const unsigned*)&xlr[(size_t)s0 * 128 + 2 * c2];
        unsigned u1 = *(const unsigned*)&xlr[(size_t)s1 * 128 + 2 * c2];
        ax += p0 * LOF(u0) + p1 * LOF(u1);
        ay += p0 * HIF(u0) + p1 * HIF(u1);
        s += p0 + p1;
    }
    for (; j < end; j += 4) {
        float2 e0 = ((const float2*)spk)[j];
        int src = __float_as_int(e0.x);
        float pj = e0.y;
        unsigned u = *(const unsigned*)&xlr[(size_t)src * 128 + 2 * c2];
        ax += pj * LOF(u);
        ay += pj * HIF(u);
        s += pj;
    }
    ax += __shfl_xor(ax, 32, 64);
    ay += __shfl_xor(ay, 32, 64);
    s  += __shfl_xor(s, 32, 64);
    if (wv == 1 && half == 0) { comb[0][c2] = ax; comb[1][c2] = ay; comb[2][c2] = s; }
    __syncthreads();
    if (wv == 0 && half == 0) {
        ax += comb[0][c2]; ay += comb[1][c2]; s += comb[2][c2];
        float inv = 1.f / s;
        float2 bb = ((const float2*)bias)[c2];
        float2 mm = ((const float2*)m)[c2];
        float2 vv = ((const float2*)v)[c2];
        float2 gg = ((const float2*)g)[c2];
        float2 bb2 = ((const float2*)b)[c2];
        float ox = ax * inv + bb.x, oy = ay * inv + bb.y;
        ox = (ox - mm.x) * rsqrtf(vv.x + 1e-5f) * gg.x + bb2.x;
        oy = (oy - mm.y) * rsqrtf(vv.y + 1e-5f) * gg.y + bb2.y;
        ox = (ox > 0.f) ? ox : (__expf(ox) - 1.f);
        oy = (oy > 0.f) ? oy : (__expf(oy) - 1.f);
        float2 wc = ((const float2*)Wc)[c2];
        float z = ox * wc.x + oy * wc.y;
        z += __shfl_xor(z, 16, 64);
        z += __shfl_xor(z, 8, 64);
        z += __shfl_xor(z, 4, 64);
        z += __shfl_xor(z, 2, 64);
        z += __shfl_xor(z, 1, 64);
        if (lane == 0) out[i] = 1.f / (1.f + __expf(-(z + bc[0])));
    }
}

// ---------------- launch ----------------

extern "C" void kernel_launch(void* const* d_in, const int* in_sizes, int n_in,
                              void* d_out, int out_size, void* d_ws, size_t ws_size,
                              hipStream_t stream) {
    const float* x    = (const float*)d_in[0];
    const int*   ei   = (const int*)d_in[1];
    const float* W1l  = (const float*)d_in[2];
    const float* b1l  = (const float*)d_in[3];
    const float* W1r  = (const float*)d_in[4];
    const float* b1r  = (const float*)d_in[5];
    const float* att1 = (const float*)d_in[6];
    const float* bias1= (const float*)d_in[7];
    const float* bn1g = (const float*)d_in[8];
    const float* bn1b = (const float*)d_in[9];
    const float* bn1m = (const float*)d_in[10];
    const float* bn1v = (const float*)d_in[11];
    const float* W2l  = (const float*)d_in[12];
    const float* b2l  = (const float*)d_in[13];
    const float* W2r  = (const float*)d_in[14];
    const float* b2r  = (const float*)d_in[15];
    const float* att2 = (const float*)d_in[16];
    const float* bias2= (const float*)d_in[17];
    const float* bn2g = (const float*)d_in[18];
    const float* bn2b = (const float*)d_in[19];
    const float* bn2m = (const float*)d_in[20];
    const float* bn2v = (const float*)d_in[21];
    const float* Wc   = (const float*)d_in[22];
    const float* bc   = (const float*)d_in[23];
    float* out = (float*)d_out;

    char* ws = (char*)d_ws;
    size_t off = 0;
    auto alloc = [&](size_t bytes) {
        size_t o = off;
        off += (bytes + 255) & ~(size_t)255;
        return o;
    };
    ushort_t* xb    = (ushort_t*)(ws + alloc((size_t)(NN + 128) * 256 * 2));
    ushort_t* xlr1  = (ushort_t*)(ws + alloc((size_t)NN * 256 * 2));  // reused as xlr2
    ushort_t* h1b   = (ushort_t*)(ws + alloc((size_t)(NN + 128) * 128 * 2));
    ushort_t* Wt1   = (ushort_t*)(ws + alloc((size_t)256 * 256 * 2));
    float*    biasf1= (float*)(ws + alloc(256 * 4));
    ushort_t* Wt2   = (ushort_t*)(ws + alloc((size_t)128 * 128 * 2));
    float*    biasf2= (float*)(ws + alloc(128 * 4));
    int* deg      = (int*)(ws + alloc((size_t)NN * 4));
    int* incl     = (int*)(ws + alloc((size_t)NN * 4));
    int* rowstart = (int*)(ws + alloc((size_t)(NN + 1) * 4));
    int* writeptr = (int*)(ws + alloc((size_t)NN * 4));
    int* totals   = (int*)(ws + alloc(64 * 4));
    int* chunkoff = (int*)(ws + alloc(64 * 4));
    int* posarr   = (int*)(ws + alloc((size_t)TE * 4));
    // spk1 (16B/edge) aliases xb: xb is dead after GEMM1, spk1 written in k_edge1 (after).
    float* spk1 = (float*)xb;                 // TE * float4 = 13.6 MB <= 25.6 MB
    float* spk2 = spk1;                       // TE * float2 (layer 2)
    ushort_t* xlr2 = xlr1;

    // CSR build
    k_zero<<<(NN + 255) / 256, 256, 0, stream>>>(deg, NN);
    k_count<<<(TE + 255) / 256, 256, 0, stream>>>(ei, deg);
    k_scan1<<<NCHUNK, 1024, 0, stream>>>(deg, incl, totals);
    k_scan2<<<1, 64, 0, stream>>>(totals, chunkoff);
    k_scan3<<<(NN + 255) / 256, 256, 0, stream>>>(incl, deg, chunkoff, rowstart, writeptr);
    k_pos<<<(TE + 255) / 256, 256, 0, stream>>>(ei, writeptr, posarr);

    // bf16 prep
    int n4x = NN * INC / 4;
    k_cast4<<<(n4x + 255) / 256, 256, 0, stream>>>(x, xb, n4x);
    k_prep_w<<<256, 256, 0, stream>>>(W1l, W1r, b1l, b1r, Wt1, biasf1, 256, 128);
    k_prep_w<<<128, 128, 0, stream>>>(W2l, W2r, b2l, b2r, Wt2, biasf2, 128, 64);

    int eb = (TE + 63) / 64;

    // layer 1
    dim3 gg1((NN + 127) / 128, 2);
    k_gemm_mfma<256, 256><<<gg1, 256, 0, stream>>>(xb, Wt1, biasf1, xlr1, NN);
    k_edge<256, 4, 2><<<eb, 256, 0, stream>>>(xlr1, ei, posarr, att1, spk1);
    k_aggr1<<<NN, 128, 0, stream>>>(xlr1, spk1, rowstart, bias1,
                                    bn1g, bn1b, bn1m, bn1v, h1b);

    // layer 2 (+classifier)
    dim3 gg2((NN + 127) / 128, 1);
    k_gemm_mfma<128, 128><<<gg2, 256, 0, stream>>>(h1b, Wt2, biasf2, xlr2, NN);
    k_edge<128, 2, 1><<<eb, 256, 0, stream>>>(xlr2, ei, posarr, att2, spk2);
    k_aggr2<<<NN, 128, 0, stream>>>(xlr2, spk2, rowstart, bias2,
                                    bn2g, bn2b, bn2m, bn2v, Wc, bc, out);
}

// Round 7
// 376.488 us; speedup vs baseline: 1.1952x; 1.1952x over previous
//
#include <hip/hip_runtime.h>
#include <hip/hip_bf16.h>
#include <cstddef>

#define NN 50000
#define EE 800000
#define TE 850000   // EE + NN self loops
#define INC 256
#define C1 128      // heads(2) * hid(64)
#define C2 64
#define NCHUNK 49   // ceil(NN/1024)

typedef unsigned short ushort_t;
typedef short bf16x8 __attribute__((ext_vector_type(8)));
typedef float f32x4 __attribute__((ext_vector_type(4)));

__device__ inline ushort_t bf16r(float f) {  // RNE float->bf16
    unsigned u = __float_as_uint(f);
    unsigned r = (u + 0x7fffu + ((u >> 16) & 1u)) >> 16;
    return (ushort_t)r;
}
#define BF2F(u) (__uint_as_float(((unsigned)(u)) << 16))
#define LOF(u) (__uint_as_float((u) << 16))           // low bf16 of packed uint
#define HIF(u) (__uint_as_float((u) & 0xffff0000u))   // high bf16 of packed uint

// ---------------- CSR build ----------------

__global__ void k_zero(int* p, int n) {
    int i = blockIdx.x * blockDim.x + threadIdx.x;
    if (i < n) p[i] = 0;
}

// count + per-edge rank within its dst bucket (rank write is coalesced)
__global__ void k_count(const int* __restrict__ ei, int* __restrict__ deg,
                        int* __restrict__ rank) {
    int e = blockIdx.x * blockDim.x + threadIdx.x;
    if (e >= TE) return;
    int dst = (e < EE) ? ei[EE + e] : (e - EE);
    rank[e] = atomicAdd(&deg[dst], 1);
}

__global__ void k_scan1(const int* __restrict__ deg, int* __restrict__ incl,
                        int* __restrict__ totals) {
    __shared__ int lds[1024];
    int t = threadIdx.x;
    int i = blockIdx.x * 1024 + t;
    int v = (i < NN) ? deg[i] : 0;
    lds[t] = v;
    __syncthreads();
    for (int off = 1; off < 1024; off <<= 1) {
        int add = (t >= off) ? lds[t - off] : 0;
        __syncthreads();
        lds[t] += add;
        __syncthreads();
    }
    if (i < NN) incl[i] = lds[t];
    if (t == 1023) totals[blockIdx.x] = lds[t];
}

__global__ void k_scan2(const int* __restrict__ totals, int* __restrict__ chunkoff) {
    int t = threadIdx.x;
    int orig = (t < NCHUNK) ? totals[t] : 0;
    int v = orig;
    for (int off = 1; off < 64; off <<= 1) {
        int u = __shfl_up(v, off, 64);
        if (t >= off) v += u;
    }
    if (t < NCHUNK) chunkoff[t] = v - orig;
}

__global__ void k_scan3(const int* __restrict__ incl, const int* __restrict__ deg,
                        const int* __restrict__ chunkoff, int* __restrict__ rowstart) {
    int i = blockIdx.x * blockDim.x + threadIdx.x;
    if (i == 0) rowstart[NN] = TE;
    if (i >= NN) return;
    rowstart[i] = incl[i] - deg[i] + chunkoff[i >> 10];
}

// atomic-free scatter: ONE independent 4B random store per edge
__global__ void k_scatter(const int* __restrict__ ei, const int* __restrict__ rank,
                          const int* __restrict__ rowstart, int* __restrict__ ssrc) {
    int e = blockIdx.x * blockDim.x + threadIdx.x;
    if (e >= TE) return;
    int s, d;
    if (e < EE) { s = ei[e]; d = ei[EE + e]; }
    else        { s = e - EE; d = s; }
    ssrc[rowstart[d] + rank[e]] = s;
}

// coalesced-ish CSR-ordered dst fill (replaces the random sdst store)
__global__ void k_filldst(const int* __restrict__ rowstart, int* __restrict__ sdst) {
    int i = blockIdx.x * blockDim.x + threadIdx.x;
    if (i >= NN) return;
    int rs = rowstart[i], re = rowstart[i + 1];
    for (int j = rs; j < re; j++) sdst[j] = i;
}

// ---------------- casts / weight prep ----------------

__global__ void k_cast4(const float* __restrict__ src, ushort_t* __restrict__ dst, int n4) {
    int i = blockIdx.x * blockDim.x + threadIdx.x;
    if (i >= n4) return;
    float4 a = ((const float4*)src)[i];
    ushort4 o;
    o.x = bf16r(a.x); o.y = bf16r(a.y); o.z = bf16r(a.z); o.w = bf16r(a.w);
    ((ushort4*)dst)[i] = o;
}

__global__ void k_prep_w(const float* __restrict__ Wl, const float* __restrict__ Wr,
                         const float* __restrict__ bl, const float* __restrict__ br,
                         ushort_t* __restrict__ Wt, float* __restrict__ biasf,
                         int K, int HALF) {
    int n = blockIdx.x;
    int k = threadIdx.x;
    const float* W = (n < HALF) ? Wl : Wr;
    int c = (n < HALF) ? n : n - HALF;
    Wt[(size_t)n * K + k] = bf16r(W[(size_t)k * HALF + c]);
    if (n == 0 && k < 2 * HALF) biasf[k] = (k < HALF) ? bl[k] : br[k - HALF];
}

// ---------------- bf16 MFMA GEMM ----------------
// C[M,NCOL](bf16) = A[M,K](bf16) @ Bt[NCOL,K]^T + bias(fp32)
// 128x128 tile, BK=32, 256 threads, 16x16x32 MFMA; LDS rows padded to 40 bf16.

template <int K, int NCOL>
__global__ __launch_bounds__(256) void k_gemm_mfma(const ushort_t* __restrict__ A,
                                                   const ushort_t* __restrict__ Bt,
                                                   const float* __restrict__ bias,
                                                   ushort_t* __restrict__ C, int M) {
    __shared__ __align__(16) ushort_t As[128 * 40];
    __shared__ __align__(16) ushort_t Bs[128 * 40];
    int tid = threadIdx.x;
    int bm = blockIdx.x * 128;
    int bn = blockIdx.y * 128;
    int w = tid >> 6, l = tid & 63;
    int wm = (w & 1) * 64, wn = (w >> 1) * 64;
    int lm = l & 15, half = l >> 4;

    f32x4 zero = {0.f, 0.f, 0.f, 0.f};
    f32x4 acc[4][4];
#pragma unroll
    for (int a = 0; a < 4; a++)
#pragma unroll
        for (int b = 0; b < 4; b++) acc[a][b] = zero;

    for (int k0 = 0; k0 < K; k0 += 32) {
#pragma unroll
        for (int q = 0; q < 2; q++) {
            int seg = q * 256 + tid;
            int m = seg >> 2;
            int ko = (seg & 3) * 8;
            *(float4*)&As[m * 40 + ko] = *(const float4*)&A[(size_t)(bm + m) * K + k0 + ko];
            *(float4*)&Bs[m * 40 + ko] = *(const float4*)&Bt[(size_t)(bn + m) * K + k0 + ko];
        }
        __syncthreads();
        bf16x8 af[4], bfr[4];
#pragma unroll
        for (int mi = 0; mi < 4; mi++)
            af[mi] = *(const bf16x8*)&As[(wm + mi * 16 + lm) * 40 + half * 8];
#pragma unroll
        for (int ni = 0; ni < 4; ni++)
            bfr[ni] = *(const bf16x8*)&Bs[(wn + ni * 16 + lm) * 40 + half * 8];
#pragma unroll
        for (int mi = 0; mi < 4; mi++)
#pragma unroll
            for (int ni = 0; ni < 4; ni++)
                acc[mi][ni] = __builtin_amdgcn_mfma_f32_16x16x32_bf16(
                    af[mi], bfr[ni], acc[mi][ni], 0, 0, 0);
        __syncthreads();
    }
#pragma unroll
    for (int ni = 0; ni < 4; ni++) {
        int col = bn + wn + ni * 16 + lm;
        float bv = bias[col];
#pragma unroll
        for (int mi = 0; mi < 4; mi++) {
            int rbase = bm + wm + mi * 16 + half * 4;
#pragma unroll
            for (int r = 0; r < 4; r++) {
                int row = rbase + r;
                if (row < M) C[(size_t)row * NCOL + col] = bf16r(acc[mi][ni][r] + bv);
            }
        }
    }
}

// ---------------- Pass A: edge-parallel logits (CSR order for dst locality) ----------------
// 4 lanes per edge; lane q covers chunk c = q + 4*it (8 channels each).
// Consecutive j share dst -> xr row L1-hit. Writes packed {src,p...} coalesced at spk[j].

__device__ inline float lrelu_dot2(unsigned ua, unsigned ub, float at_lo, float at_hi) {
    float alo = __uint_as_float(ua << 16), ahi = __uint_as_float(ua & 0xffff0000u);
    float blo = __uint_as_float(ub << 16), bhi = __uint_as_float(ub & 0xffff0000u);
    float t0 = alo + blo, t1 = ahi + bhi;
    float l0 = fmaxf(t0, 0.f) + 0.2f * fminf(t0, 0.f);
    float l1 = fmaxf(t1, 0.f) + 0.2f * fminf(t1, 0.f);
    return at_lo * l0 + at_hi * l1;
}

template <int STRIDE, int ITS, int HEADS>
__global__ __launch_bounds__(256) void k_edge(
    const ushort_t* __restrict__ xlr,
    const int* __restrict__ ssrc, const int* __restrict__ sdst,
    const float* __restrict__ att, float* __restrict__ spk) {
    int l = threadIdx.x & 63;
    int wv = threadIdx.x >> 6;
    int q = l & 3;
    int j = blockIdx.x * 64 + wv * 16 + (l >> 2);
    if (j >= TE) return;
    int src = ssrc[j], dst = sdst[j];
    const ushort_t* xl = xlr + (size_t)src * STRIDE;
    const ushort_t* xr = xlr + (size_t)dst * STRIDE + STRIDE / 2;
    float w[HEADS];
#pragma unroll
    for (int h = 0; h < HEADS; h++) w[h] = 0.f;
#pragma unroll
    for (int it = 0; it < ITS; it++) {
        int c = q + 4 * it;  // chunk of 8 channels
        uint4 a = *(const uint4*)&xl[c * 8];
        uint4 b = *(const uint4*)&xr[c * 8];
        float4 t0 = *(const float4*)&att[c * 8];
        float4 t1 = *(const float4*)&att[c * 8 + 4];
        int h = (HEADS == 2 && it >= ITS / 2) ? 1 : 0;
        float d = lrelu_dot2(a.x, b.x, t0.x, t0.y)
                + lrelu_dot2(a.y, b.y, t0.z, t0.w)
                + lrelu_dot2(a.z, b.z, t1.x, t1.y)
                + lrelu_dot2(a.w, b.w, t1.z, t1.w);
        w[h] += d;
    }
#pragma unroll
    for (int h = 0; h < HEADS; h++) {
        w[h] += __shfl_xor(w[h], 1, 64);
        w[h] += __shfl_xor(w[h], 2, 64);
    }
    if (q == 0) {
        if (HEADS == 2) {
            ((float4*)spk)[j] = make_float4(__int_as_float(src), __expf(w[0]), __expf(w[1]), 0.f);
        } else {
            ((float2*)spk)[j] = make_float2(__int_as_float(src), __expf(w[0]));
        }
    }
}

// ---------------- Pass B: node-parallel aggregation + epilogue ----------------
// Lane loads a packed uint = 2 bf16 channels; one 16B/8B broadcast per edge for {src,p}.

// Layer 1: block 128 = 2 waves, one node; wave w owns edges {row+w, row+w+2, ...}.
// Lane covers channels {2*lane, 2*lane+1}; head = lane>>5.
__global__ __launch_bounds__(128) void k_aggr1(
    const ushort_t* __restrict__ xlr, const float* __restrict__ spk,
    const int* __restrict__ rowstart,
    const float* __restrict__ bias,
    const float* __restrict__ g, const float* __restrict__ b,
    const float* __restrict__ m, const float* __restrict__ v,
    ushort_t* __restrict__ out) {
    __shared__ float comb[3][64];
    int i = blockIdx.x;
    int lane = threadIdx.x & 63;
    int wv = threadIdx.x >> 6;
    int head = lane >> 5;
    int row = rowstart[i], end = rowstart[i + 1];
    float ax = 0.f, ay = 0.f, s = 0.f;
    int j = row + wv;
    for (; j + 6 < end; j += 8) {  // 4 edges per wave per iter (stride 2)
        float4 e0 = ((const float4*)spk)[j],     e1 = ((const float4*)spk)[j + 2];
        float4 e2 = ((const float4*)spk)[j + 4], e3 = ((const float4*)spk)[j + 6];
        int s0 = __float_as_int(e0.x), s1 = __float_as_int(e1.x);
        int s2 = __float_as_int(e2.x), s3 = __float_as_int(e3.x);
        float p0 = head ? e0.z : e0.y, p1 = head ? e1.z : e1.y;
        float p2 = head ? e2.z : e2.y, p3 = head ? e3.z : e3.y;
        unsigned u0 = *(const unsigned*)&xlr[(size_t)s0 * 256 + 2 * lane];
        unsigned u1 = *(const unsigned*)&xlr[(size_t)s1 * 256 + 2 * lane];
        unsigned u2 = *(const unsigned*)&xlr[(size_t)s2 * 256 + 2 * lane];
        unsigned u3 = *(const unsigned*)&xlr[(size_t)s3 * 256 + 2 * lane];
        ax += p0 * LOF(u0) + p1 * LOF(u1) + p2 * LOF(u2) + p3 * LOF(u3);
        ay += p0 * HIF(u0) + p1 * HIF(u1) + p2 * HIF(u2) + p3 * HIF(u3);
        s += (p0 + p1) + (p2 + p3);
    }
    for (; j < end; j += 2) {
        float4 e0 = ((const float4*)spk)[j];
        int src = __float_as_int(e0.x);
        float pj = head ? e0.z : e0.y;
        unsigned u = *(const unsigned*)&xlr[(size_t)src * 256 + 2 * lane];
        ax += pj * LOF(u);
        ay += pj * HIF(u);
        s += pj;
    }
    if (wv == 1) { comb[0][lane] = ax; comb[1][lane] = ay; comb[2][lane] = s; }
    __syncthreads();
    if (wv == 0) {
        ax += comb[0][lane]; ay += comb[1][lane]; s += comb[2][lane];
        float inv = 1.f / s;
        float2 bb = ((const float2*)bias)[lane];
        float2 mm = ((const float2*)m)[lane];
        float2 vv = ((const float2*)v)[lane];
        float2 gg = ((const float2*)g)[lane];
        float2 bb2 = ((const float2*)b)[lane];
        float ox = ax * inv + bb.x, oy = ay * inv + bb.y;
        ox = (ox - mm.x) * rsqrtf(vv.x + 1e-5f) * gg.x + bb2.x;
        oy = (oy - mm.y) * rsqrtf(vv.y + 1e-5f) * gg.y + bb2.y;
        ox = (ox > 0.f) ? ox : (__expf(ox) - 1.f);
        oy = (oy > 0.f) ? oy : (__expf(oy) - 1.f);
        unsigned wpack = (unsigned)bf16r(ox) | ((unsigned)bf16r(oy) << 16);
        *(unsigned*)&out[(size_t)i * C1 + 2 * lane] = wpack;
    }
}

// Layer 2 + classifier: block 128 = 2 waves, one node; 4 edge slots (wave x half-wave).
// c2 = lane&31 covers channels {2*c2, 2*c2+1}.
__global__ __launch_bounds__(128) void k_aggr2(
    const ushort_t* __restrict__ xlr, const float* __restrict__ spk,
    const int* __restrict__ rowstart,
    const float* __restrict__ bias,
    const float* __restrict__ g, const float* __restrict__ b,
    const float* __restrict__ m, const float* __restrict__ v,
    const float* __restrict__ Wc, const float* __restrict__ bc,
    float* __restrict__ out) {
    __shared__ float comb[3][32];
    int i = blockIdx.x;
    int lane = threadIdx.x & 63;
    int wv = threadIdx.x >> 6;
    int half = lane >> 5;
    int c2 = lane & 31;
    int row = rowstart[i], end = rowstart[i + 1];
    float ax = 0.f, ay = 0.f, s = 0.f;
    int j = row + wv * 2 + half;
    for (; j + 4 < end; j += 8) {  // 2 edges per slot per iter (stride 4)
        float2 e0 = ((const float2*)spk)[j], e1 = ((const float2*)spk)[j + 4];
        int s0 = __float_as_int(e0.x), s1 = __float_as_int(e1.x);
        float p0 = e0.y, p1 = e1.y;
        unsigned u0 = *(const unsigned*)&xlr[(size_t)s0 * 128 + 2 * c2];
        unsigned u1 = *(const unsigned*)&xlr[(size_t)s1 * 128 + 2 * c2];
        ax += p0 * LOF(u0) + p1 * LOF(u1);
        ay += p0 * HIF(u0) + p1 * HIF(u1);
        s += p0 + p1;
    }
    for (; j < end; j += 4) {
        float2 e0 = ((const float2*)spk)[j];
        int src = __float_as_int(e0.x);
        float pj = e0.y;
        unsigned u = *(const unsigned*)&xlr[(size_t)src * 128 + 2 * c2];
        ax += pj * LOF(u);
        ay += pj * HIF(u);
        s += pj;
    }
    ax += __shfl_xor(ax, 32, 64);
    ay += __shfl_xor(ay, 32, 64);
    s  += __shfl_xor(s, 32, 64);
    if (wv == 1 && half == 0) { comb[0][c2] = ax; comb[1][c2] = ay; comb[2][c2] = s; }
    __syncthreads();
    if (wv == 0 && half == 0) {
        ax += comb[0][c2]; ay += comb[1][c2]; s += comb[2][c2];
        float inv = 1.f / s;
        float2 bb = ((const float2*)bias)[c2];
        float2 mm = ((const float2*)m)[c2];
        float2 vv = ((const float2*)v)[c2];
        float2 gg = ((const float2*)g)[c2];
        float2 bb2 = ((const float2*)b)[c2];
        float ox = ax * inv + bb.x, oy = ay * inv + bb.y;
        ox = (ox - mm.x) * rsqrtf(vv.x + 1e-5f) * gg.x + bb2.x;
        oy = (oy - mm.y) * rsqrtf(vv.y + 1e-5f) * gg.y + bb2.y;
        ox = (ox > 0.f) ? ox : (__expf(ox) - 1.f);
        oy = (oy > 0.f) ? oy : (__expf(oy) - 1.f);
        float2 wc = ((const float2*)Wc)[c2];
        float z = ox * wc.x + oy * wc.y;
        z += __shfl_xor(z, 16, 64);
        z += __shfl_xor(z, 8, 64);
        z += __shfl_xor(z, 4, 64);
        z += __shfl_xor(z, 2, 64);
        z += __shfl_xor(z, 1, 64);
        if (lane == 0) out[i] = 1.f / (1.f + __expf(-(z + bc[0])));
    }
}

// ---------------- launch ----------------

extern "C" void kernel_launch(void* const* d_in, const int* in_sizes, int n_in,
                              void* d_out, int out_size, void* d_ws, size_t ws_size,
                              hipStream_t stream) {
    const float* x    = (const float*)d_in[0];
    const int*   ei   = (const int*)d_in[1];
    const float* W1l  = (const float*)d_in[2];
    const float* b1l  = (const float*)d_in[3];
    const float* W1r  = (const float*)d_in[4];
    const float* b1r  = (const float*)d_in[5];
    const float* att1 = (const float*)d_in[6];
    const float* bias1= (const float*)d_in[7];
    const float* bn1g = (const float*)d_in[8];
    const float* bn1b = (const float*)d_in[9];
    const float* bn1m = (const float*)d_in[10];
    const float* bn1v = (const float*)d_in[11];
    const float* W2l  = (const float*)d_in[12];
    const float* b2l  = (const float*)d_in[13];
    const float* W2r  = (const float*)d_in[14];
    const float* b2r  = (const float*)d_in[15];
    const float* att2 = (const float*)d_in[16];
    const float* bias2= (const float*)d_in[17];
    const float* bn2g = (const float*)d_in[18];
    const float* bn2b = (const float*)d_in[19];
    const float* bn2m = (const float*)d_in[20];
    const float* bn2v = (const float*)d_in[21];
    const float* Wc   = (const float*)d_in[22];
    const float* bc   = (const float*)d_in[23];
    float* out = (float*)d_out;

    char* ws = (char*)d_ws;
    size_t off = 0;
    auto alloc = [&](size_t bytes) {
        size_t o = off;
        off += (bytes + 255) & ~(size_t)255;
        return o;
    };
    ushort_t* xb    = (ushort_t*)(ws + alloc((size_t)(NN + 128) * 256 * 2));
    ushort_t* xlr1  = (ushort_t*)(ws + alloc((size_t)NN * 256 * 2));  // reused as xlr2
    ushort_t* h1b   = (ushort_t*)(ws + alloc((size_t)(NN + 128) * 128 * 2));
    ushort_t* Wt1   = (ushort_t*)(ws + alloc((size_t)256 * 256 * 2));
    float*    biasf1= (float*)(ws + alloc(256 * 4));
    ushort_t* Wt2   = (ushort_t*)(ws + alloc((size_t)128 * 128 * 2));
    float*    biasf2= (float*)(ws + alloc(128 * 4));
    int* deg      = (int*)(ws + alloc((size_t)NN * 4));
    int* incl     = (int*)(ws + alloc((size_t)NN * 4));
    int* rowstart = (int*)(ws + alloc((size_t)(NN + 1) * 4));
    int* totals   = (int*)(ws + alloc(64 * 4));
    int* chunkoff = (int*)(ws + alloc(64 * 4));
    int* rank     = (int*)(ws + alloc((size_t)TE * 4));
    int* ssrc     = (int*)(ws + alloc((size_t)TE * 4));
    int* sdst     = (int*)(ws + alloc((size_t)TE * 4));
    // spk1 (16B/edge) aliases xb: xb is dead after GEMM1, spk1 written in k_edge1 (after).
    float* spk1 = (float*)xb;                 // TE * float4 = 13.6 MB <= 25.7 MB
    float* spk2 = spk1;                       // TE * float2 (layer 2)
    ushort_t* xlr2 = xlr1;

    // CSR build: one atomic pass (count+rank), scan, atomic-free scatter, dst fill
    k_zero<<<(NN + 255) / 256, 256, 0, stream>>>(deg, NN);
    k_count<<<(TE + 255) / 256, 256, 0, stream>>>(ei, deg, rank);
    k_scan1<<<NCHUNK, 1024, 0, stream>>>(deg, incl, totals);
    k_scan2<<<1, 64, 0, stream>>>(totals, chunkoff);
    k_scan3<<<(NN + 255) / 256, 256, 0, stream>>>(incl, deg, chunkoff, rowstart);
    k_scatter<<<(TE + 255) / 256, 256, 0, stream>>>(ei, rank, rowstart, ssrc);
    k_filldst<<<(NN + 255) / 256, 256, 0, stream>>>(rowstart, sdst);

    // bf16 prep
    int n4x = NN * INC / 4;
    k_cast4<<<(n4x + 255) / 256, 256, 0, stream>>>(x, xb, n4x);
    k_prep_w<<<256, 256, 0, stream>>>(W1l, W1r, b1l, b1r, Wt1, biasf1, 256, 128);
    k_prep_w<<<128, 128, 0, stream>>>(W2l, W2r, b2l, b2r, Wt2, biasf2, 128, 64);

    int eb = (TE + 63) / 64;

    // layer 1
    dim3 gg1((NN + 127) / 128, 2);
    k_gemm_mfma<256, 256><<<gg1, 256, 0, stream>>>(xb, Wt1, biasf1, xlr1, NN);
    k_edge<256, 4, 2><<<eb, 256, 0, stream>>>(xlr1, ssrc, sdst, att1, spk1);
    k_aggr1<<<NN, 128, 0, stream>>>(xlr1, spk1, rowstart, bias1,
                                    bn1g, bn1b, bn1m, bn1v, h1b);

    // layer 2 (+classifier)
    dim3 gg2((NN + 127) / 128, 1);
    k_gemm_mfma<128, 128><<<gg2, 256, 0, stream>>>(h1b, Wt2, biasf2, xlr2, NN);
    k_edge<128, 2, 1><<<eb, 256, 0, stream>>>(xlr2, ssrc, sdst, att2, spk2);
    k_aggr2<<<NN, 128, 0, stream>>>(xlr2, spk2, rowstart, bias2,
                                    bn2g, bn2b, bn2m, bn2v, Wc, bc, out);
}

// Round 8
// 355.960 us; speedup vs baseline: 1.2641x; 1.0577x over previous
//
#include <hip/hip_runtime.h>
#include <hip/hip_bf16.h>
#include <cstddef>

#define NN 50000
#define EE 800000
#define TE 850000   // EE + NN self loops
#define INC 256
#define C1 128      // heads(2) * hid(64)
#define C2 64
#define NCHUNK 49   // ceil(NN/1024)

typedef unsigned short ushort_t;
typedef short bf16x8 __attribute__((ext_vector_type(8)));
typedef float f32x4 __attribute__((ext_vector_type(4)));

__device__ inline ushort_t bf16r(float f) {  // RNE float->bf16
    unsigned u = __float_as_uint(f);
    unsigned r = (u + 0x7fffu + ((u >> 16) & 1u)) >> 16;
    return (ushort_t)r;
}
#define BF2F(u) (__uint_as_float(((unsigned)(u)) << 16))
#define LOF(u) (__uint_as_float((u) << 16))           // low bf16 of packed uint
#define HIF(u) (__uint_as_float((u) & 0xffff0000u))   // high bf16 of packed uint

// ---------------- CSR build ----------------

__global__ void k_zero(int* p, int n) {
    int i = blockIdx.x * blockDim.x + threadIdx.x;
    if (i < n) p[i] = 0;
}

// count + per-edge rank within its dst bucket (rank write is coalesced)
__global__ void k_count(const int* __restrict__ ei, int* __restrict__ deg,
                        int* __restrict__ rank) {
    int e = blockIdx.x * blockDim.x + threadIdx.x;
    if (e >= TE) return;
    int dst = (e < EE) ? ei[EE + e] : (e - EE);
    rank[e] = atomicAdd(&deg[dst], 1);
}

__global__ void k_scan1(const int* __restrict__ deg, int* __restrict__ incl,
                        int* __restrict__ totals) {
    __shared__ int lds[1024];
    int t = threadIdx.x;
    int i = blockIdx.x * 1024 + t;
    int v = (i < NN) ? deg[i] : 0;
    lds[t] = v;
    __syncthreads();
    for (int off = 1; off < 1024; off <<= 1) {
        int add = (t >= off) ? lds[t - off] : 0;
        __syncthreads();
        lds[t] += add;
        __syncthreads();
    }
    if (i < NN) incl[i] = lds[t];
    if (t == 1023) totals[blockIdx.x] = lds[t];
}

__global__ void k_scan2(const int* __restrict__ totals, int* __restrict__ chunkoff) {
    int t = threadIdx.x;
    int orig = (t < NCHUNK) ? totals[t] : 0;
    int v = orig;
    for (int off = 1; off < 64; off <<= 1) {
        int u = __shfl_up(v, off, 64);
        if (t >= off) v += u;
    }
    if (t < NCHUNK) chunkoff[t] = v - orig;
}

__global__ void k_scan3(const int* __restrict__ incl, const int* __restrict__ deg,
                        const int* __restrict__ chunkoff, int* __restrict__ rowstart) {
    int i = blockIdx.x * blockDim.x + threadIdx.x;
    if (i == 0) rowstart[NN] = TE;
    if (i >= NN) return;
    rowstart[i] = incl[i] - deg[i] + chunkoff[i >> 10];
}

// atomic-free scatter: ONE independent 4B random store per edge
__global__ void k_scatter(const int* __restrict__ ei, const int* __restrict__ rank,
                          const int* __restrict__ rowstart, int* __restrict__ ssrc) {
    int e = blockIdx.x * blockDim.x + threadIdx.x;
    if (e >= TE) return;
    int s, d;
    if (e < EE) { s = ei[e]; d = ei[EE + e]; }
    else        { s = e - EE; d = s; }
    ssrc[rowstart[d] + rank[e]] = s;
}

// coalesced-ish CSR-ordered dst fill (replaces the random sdst store)
__global__ void k_filldst(const int* __restrict__ rowstart, int* __restrict__ sdst) {
    int i = blockIdx.x * blockDim.x + threadIdx.x;
    if (i >= NN) return;
    int rs = rowstart[i], re = rowstart[i + 1];
    for (int j = rs; j < re; j++) sdst[j] = i;
}

// ---------------- casts / weight prep ----------------

__global__ void k_cast4(const float* __restrict__ src, ushort_t* __restrict__ dst, int n4) {
    int i = blockIdx.x * blockDim.x + threadIdx.x;
    if (i >= n4) return;
    float4 a = ((const float4*)src)[i];
    ushort4 o;
    o.x = bf16r(a.x); o.y = bf16r(a.y); o.z = bf16r(a.z); o.w = bf16r(a.w);
    ((ushort4*)dst)[i] = o;
}

__global__ void k_prep_w(const float* __restrict__ Wl, const float* __restrict__ Wr,
                         const float* __restrict__ bl, const float* __restrict__ br,
                         ushort_t* __restrict__ Wt, float* __restrict__ biasf,
                         int K, int HALF) {
    int n = blockIdx.x;
    int k = threadIdx.x;
    const float* W = (n < HALF) ? Wl : Wr;
    int c = (n < HALF) ? n : n - HALF;
    Wt[(size_t)n * K + k] = bf16r(W[(size_t)k * HALF + c]);
    if (n == 0 && k < 2 * HALF) biasf[k] = (k < HALF) ? bl[k] : br[k - HALF];
}

// ---------------- bf16 MFMA GEMM ----------------
// C[M,NCOL](bf16) = A[M,K](bf16) @ Bt[NCOL,K]^T + bias(fp32)
// 128x128 tile, BK=32, 256 threads, 16x16x32 MFMA; LDS rows padded to 40 bf16.

template <int K, int NCOL>
__global__ __launch_bounds__(256) void k_gemm_mfma(const ushort_t* __restrict__ A,
                                                   const ushort_t* __restrict__ Bt,
                                                   const float* __restrict__ bias,
                                                   ushort_t* __restrict__ C, int M) {
    __shared__ __align__(16) ushort_t As[128 * 40];
    __shared__ __align__(16) ushort_t Bs[128 * 40];
    int tid = threadIdx.x;
    int bm = blockIdx.x * 128;
    int bn = blockIdx.y * 128;
    int w = tid >> 6, l = tid & 63;
    int wm = (w & 1) * 64, wn = (w >> 1) * 64;
    int lm = l & 15, half = l >> 4;

    f32x4 zero = {0.f, 0.f, 0.f, 0.f};
    f32x4 acc[4][4];
#pragma unroll
    for (int a = 0; a < 4; a++)
#pragma unroll
        for (int b = 0; b < 4; b++) acc[a][b] = zero;

    for (int k0 = 0; k0 < K; k0 += 32) {
#pragma unroll
        for (int q = 0; q < 2; q++) {
            int seg = q * 256 + tid;
            int m = seg >> 2;
            int ko = (seg & 3) * 8;
            *(float4*)&As[m * 40 + ko] = *(const float4*)&A[(size_t)(bm + m) * K + k0 + ko];
            *(float4*)&Bs[m * 40 + ko] = *(const float4*)&Bt[(size_t)(bn + m) * K + k0 + ko];
        }
        __syncthreads();
        bf16x8 af[4], bfr[4];
#pragma unroll
        for (int mi = 0; mi < 4; mi++)
            af[mi] = *(const bf16x8*)&As[(wm + mi * 16 + lm) * 40 + half * 8];
#pragma unroll
        for (int ni = 0; ni < 4; ni++)
            bfr[ni] = *(const bf16x8*)&Bs[(wn + ni * 16 + lm) * 40 + half * 8];
#pragma unroll
        for (int mi = 0; mi < 4; mi++)
#pragma unroll
            for (int ni = 0; ni < 4; ni++)
                acc[mi][ni] = __builtin_amdgcn_mfma_f32_16x16x32_bf16(
                    af[mi], bfr[ni], acc[mi][ni], 0, 0, 0);
        __syncthreads();
    }
#pragma unroll
    for (int ni = 0; ni < 4; ni++) {
        int col = bn + wn + ni * 16 + lm;
        float bv = bias[col];
#pragma unroll
        for (int mi = 0; mi < 4; mi++) {
            int rbase = bm + wm + mi * 16 + half * 4;
#pragma unroll
            for (int r = 0; r < 4; r++) {
                int row = rbase + r;
                if (row < M) C[(size_t)row * NCOL + col] = bf16r(acc[mi][ni][r] + bv);
            }
        }
    }
}

// ---------------- Pass A: edge-parallel logits (CSR order for dst locality) ----------------
// 4 lanes per edge; lane q covers chunk c = q + 4*it (8 channels each).
// Consecutive j share dst -> xr row L1-hit. Writes packed {src,p...} coalesced at spk[j].

__device__ inline float lrelu_dot2(unsigned ua, unsigned ub, float at_lo, float at_hi) {
    float alo = __uint_as_float(ua << 16), ahi = __uint_as_float(ua & 0xffff0000u);
    float blo = __uint_as_float(ub << 16), bhi = __uint_as_float(ub & 0xffff0000u);
    float t0 = alo + blo, t1 = ahi + bhi;
    float l0 = fmaxf(t0, 0.f) + 0.2f * fminf(t0, 0.f);
    float l1 = fmaxf(t1, 0.f) + 0.2f * fminf(t1, 0.f);
    return at_lo * l0 + at_hi * l1;
}

template <int STRIDE, int ITS, int HEADS>
__global__ __launch_bounds__(256) void k_edge(
    const ushort_t* __restrict__ xlr,
    const int* __restrict__ ssrc, const int* __restrict__ sdst,
    const float* __restrict__ att, float* __restrict__ spk) {
    int l = threadIdx.x & 63;
    int wv = threadIdx.x >> 6;
    int q = l & 3;
    int j = blockIdx.x * 64 + wv * 16 + (l >> 2);
    if (j >= TE) return;
    int src = ssrc[j], dst = sdst[j];
    const ushort_t* xl = xlr + (size_t)src * STRIDE;
    const ushort_t* xr = xlr + (size_t)dst * STRIDE + STRIDE / 2;
    float w[HEADS];
#pragma unroll
    for (int h = 0; h < HEADS; h++) w[h] = 0.f;
#pragma unroll
    for (int it = 0; it < ITS; it++) {
        int c = q + 4 * it;  // chunk of 8 channels
        uint4 a = *(const uint4*)&xl[c * 8];
        uint4 b = *(const uint4*)&xr[c * 8];
        float4 t0 = *(const float4*)&att[c * 8];
        float4 t1 = *(const float4*)&att[c * 8 + 4];
        int h = (HEADS == 2 && it >= ITS / 2) ? 1 : 0;
        float d = lrelu_dot2(a.x, b.x, t0.x, t0.y)
                + lrelu_dot2(a.y, b.y, t0.z, t0.w)
                + lrelu_dot2(a.z, b.z, t1.x, t1.y)
                + lrelu_dot2(a.w, b.w, t1.z, t1.w);
        w[h] += d;
    }
#pragma unroll
    for (int h = 0; h < HEADS; h++) {
        w[h] += __shfl_xor(w[h], 1, 64);
        w[h] += __shfl_xor(w[h], 2, 64);
    }
    if (q == 0) {
        if (HEADS == 2) {
            ((float4*)spk)[j] = make_float4(__int_as_float(src), __expf(w[0]), __expf(w[1]), 0.f);
        } else {
            ((float2*)spk)[j] = make_float2(__int_as_float(src), __expf(w[0]));
        }
    }
}

// ---------------- Pass B: node-parallel aggregation + epilogue ----------------
// One node per WAVE. p is broadcast per edge, so the softmax denom s is replicated
// in every lane -> no cross-lane/LDS combine at all. 8-edge unrolled batches give
// 8 spk loads + 8 gathers in flight per wave.

// Layer 1: 4 nodes per block (4 waves). Lane covers channels {2*lane, 2*lane+1}.
__global__ __launch_bounds__(256) void k_aggr1(
    const ushort_t* __restrict__ xlr, const float* __restrict__ spk,
    const int* __restrict__ rowstart,
    const float* __restrict__ bias,
    const float* __restrict__ g, const float* __restrict__ b,
    const float* __restrict__ m, const float* __restrict__ v,
    ushort_t* __restrict__ out) {
    int lane = threadIdx.x & 63;
    int i = blockIdx.x * 4 + (threadIdx.x >> 6);
    if (i >= NN) return;
    int head = lane >> 5;
    int row = rowstart[i], end = rowstart[i + 1];
    float ax = 0.f, ay = 0.f, s = 0.f;
    int j = row;
    for (; j + 8 <= end; j += 8) {
        float4 e[8];
        unsigned u[8];
#pragma unroll
        for (int k = 0; k < 8; k++) e[k] = ((const float4*)spk)[j + k];
#pragma unroll
        for (int k = 0; k < 8; k++)
            u[k] = *(const unsigned*)&xlr[(size_t)__float_as_int(e[k].x) * 256 + 2 * lane];
#pragma unroll
        for (int k = 0; k < 8; k++) {
            float p = head ? e[k].z : e[k].y;
            ax += p * LOF(u[k]);
            ay += p * HIF(u[k]);
            s += p;
        }
    }
    if (j + 4 <= end) {
        float4 e[4];
        unsigned u[4];
#pragma unroll
        for (int k = 0; k < 4; k++) e[k] = ((const float4*)spk)[j + k];
#pragma unroll
        for (int k = 0; k < 4; k++)
            u[k] = *(const unsigned*)&xlr[(size_t)__float_as_int(e[k].x) * 256 + 2 * lane];
#pragma unroll
        for (int k = 0; k < 4; k++) {
            float p = head ? e[k].z : e[k].y;
            ax += p * LOF(u[k]);
            ay += p * HIF(u[k]);
            s += p;
        }
        j += 4;
    }
    for (; j < end; j++) {
        float4 e0 = ((const float4*)spk)[j];
        float p = head ? e0.z : e0.y;
        unsigned u = *(const unsigned*)&xlr[(size_t)__float_as_int(e0.x) * 256 + 2 * lane];
        ax += p * LOF(u);
        ay += p * HIF(u);
        s += p;
    }
    float inv = 1.f / s;
    float2 bb = ((const float2*)bias)[lane];
    float2 mm = ((const float2*)m)[lane];
    float2 vv = ((const float2*)v)[lane];
    float2 gg = ((const float2*)g)[lane];
    float2 bb2 = ((const float2*)b)[lane];
    float ox = ax * inv + bb.x, oy = ay * inv + bb.y;
    ox = (ox - mm.x) * rsqrtf(vv.x + 1e-5f) * gg.x + bb2.x;
    oy = (oy - mm.y) * rsqrtf(vv.y + 1e-5f) * gg.y + bb2.y;
    ox = (ox > 0.f) ? ox : (__expf(ox) - 1.f);
    oy = (oy > 0.f) ? oy : (__expf(oy) - 1.f);
    unsigned wpack = (unsigned)bf16r(ox) | ((unsigned)bf16r(oy) << 16);
    *(unsigned*)&out[(size_t)i * C1 + 2 * lane] = wpack;
}

// Layer 2 + classifier: 2 nodes per wave (half-wave each), 8 nodes per block.
// c2 = lane&31 covers channels {2*c2, 2*c2+1}; 4-edge unroll -> 8 loads in flight/wave.
__global__ __launch_bounds__(256) void k_aggr2(
    const ushort_t* __restrict__ xlr, const float* __restrict__ spk,
    const int* __restrict__ rowstart,
    const float* __restrict__ bias,
    const float* __restrict__ g, const float* __restrict__ b,
    const float* __restrict__ m, const float* __restrict__ v,
    const float* __restrict__ Wc, const float* __restrict__ bc,
    float* __restrict__ out) {
    int lane = threadIdx.x & 63;
    int c2 = lane & 31;
    int i = blockIdx.x * 8 + (threadIdx.x >> 6) * 2 + (lane >> 5);
    if (i >= NN) return;
    int row = rowstart[i], end = rowstart[i + 1];
    float ax = 0.f, ay = 0.f, s = 0.f;
    int j = row;
    for (; j + 4 <= end; j += 4) {
        float2 e[4];
        unsigned u[4];
#pragma unroll
        for (int k = 0; k < 4; k++) e[k] = ((const float2*)spk)[j + k];
#pragma unroll
        for (int k = 0; k < 4; k++)
            u[k] = *(const unsigned*)&xlr[(size_t)__float_as_int(e[k].x) * 128 + 2 * c2];
#pragma unroll
        for (int k = 0; k < 4; k++) {
            ax += e[k].y * LOF(u[k]);
            ay += e[k].y * HIF(u[k]);
            s += e[k].y;
        }
    }
    for (; j < end; j++) {
        float2 e0 = ((const float2*)spk)[j];
        unsigned u = *(const unsigned*)&xlr[(size_t)__float_as_int(e0.x) * 128 + 2 * c2];
        ax += e0.y * LOF(u);
        ay += e0.y * HIF(u);
        s += e0.y;
    }
    float inv = 1.f / s;
    float2 bb = ((const float2*)bias)[c2];
    float2 mm = ((const float2*)m)[c2];
    float2 vv = ((const float2*)v)[c2];
    float2 gg = ((const float2*)g)[c2];
    float2 bb2 = ((const float2*)b)[c2];
    float ox = ax * inv + bb.x, oy = ay * inv + bb.y;
    ox = (ox - mm.x) * rsqrtf(vv.x + 1e-5f) * gg.x + bb2.x;
    oy = (oy - mm.y) * rsqrtf(vv.y + 1e-5f) * gg.y + bb2.y;
    ox = (ox > 0.f) ? ox : (__expf(ox) - 1.f);
    oy = (oy > 0.f) ? oy : (__expf(oy) - 1.f);
    float2 wc = ((const float2*)Wc)[c2];
    float z = ox * wc.x + oy * wc.y;
    z += __shfl_xor(z, 16, 64);  // xor<32: stays within the half-wave
    z += __shfl_xor(z, 8, 64);
    z += __shfl_xor(z, 4, 64);
    z += __shfl_xor(z, 2, 64);
    z += __shfl_xor(z, 1, 64);
    if (c2 == 0) out[i] = 1.f / (1.f + __expf(-(z + bc[0])));
}

// ---------------- launch ----------------

extern "C" void kernel_launch(void* const* d_in, const int* in_sizes, int n_in,
                              void* d_out, int out_size, void* d_ws, size_t ws_size,
                              hipStream_t stream) {
    const float* x    = (const float*)d_in[0];
    const int*   ei   = (const int*)d_in[1];
    const float* W1l  = (const float*)d_in[2];
    const float* b1l  = (const float*)d_in[3];
    const float* W1r  = (const float*)d_in[4];
    const float* b1r  = (const float*)d_in[5];
    const float* att1 = (const float*)d_in[6];
    const float* bias1= (const float*)d_in[7];
    const float* bn1g = (const float*)d_in[8];
    const float* bn1b = (const float*)d_in[9];
    const float* bn1m = (const float*)d_in[10];
    const float* bn1v = (const float*)d_in[11];
    const float* W2l  = (const float*)d_in[12];
    const float* b2l  = (const float*)d_in[13];
    const float* W2r  = (const float*)d_in[14];
    const float* b2r  = (const float*)d_in[15];
    const float* att2 = (const float*)d_in[16];
    const float* bias2= (const float*)d_in[17];
    const float* bn2g = (const float*)d_in[18];
    const float* bn2b = (const float*)d_in[19];
    const float* bn2m = (const float*)d_in[20];
    const float* bn2v = (const float*)d_in[21];
    const float* Wc   = (const float*)d_in[22];
    const float* bc   = (const float*)d_in[23];
    float* out = (float*)d_out;

    char* ws = (char*)d_ws;
    size_t off = 0;
    auto alloc = [&](size_t bytes) {
        size_t o = off;
        off += (bytes + 255) & ~(size_t)255;
        return o;
    };
    ushort_t* xb    = (ushort_t*)(ws + alloc((size_t)(NN + 128) * 256 * 2));
    ushort_t* xlr1  = (ushort_t*)(ws + alloc((size_t)NN * 256 * 2));  // reused as xlr2
    ushort_t* h1b   = (ushort_t*)(ws + alloc((size_t)(NN + 128) * 128 * 2));
    ushort_t* Wt1   = (ushort_t*)(ws + alloc((size_t)256 * 256 * 2));
    float*    biasf1= (float*)(ws + alloc(256 * 4));
    ushort_t* Wt2   = (ushort_t*)(ws + alloc((size_t)128 * 128 * 2));
    float*    biasf2= (float*)(ws + alloc(128 * 4));
    int* deg      = (int*)(ws + alloc((size_t)NN * 4));
    int* incl     = (int*)(ws + alloc((size_t)NN * 4));
    int* rowstart = (int*)(ws + alloc((size_t)(NN + 1) * 4));
    int* totals   = (int*)(ws + alloc(64 * 4));
    int* chunkoff = (int*)(ws + alloc(64 * 4));
    int* rank     = (int*)(ws + alloc((size_t)TE * 4));
    int* ssrc     = (int*)(ws + alloc((size_t)TE * 4));
    int* sdst     = (int*)(ws + alloc((size_t)TE * 4));
    // spk1 (16B/edge) aliases xb: xb is dead after GEMM1, spk1 written in k_edge1 (after).
    float* spk1 = (float*)xb;                 // TE * float4 = 13.6 MB <= 25.7 MB
    float* spk2 = spk1;                       // TE * float2 (layer 2)
    ushort_t* xlr2 = xlr1;

    // CSR build: one atomic pass (count+rank), scan, atomic-free scatter, dst fill
    k_zero<<<(NN + 255) / 256, 256, 0, stream>>>(deg, NN);
    k_count<<<(TE + 255) / 256, 256, 0, stream>>>(ei, deg, rank);
    k_scan1<<<NCHUNK, 1024, 0, stream>>>(deg, incl, totals);
    k_scan2<<<1, 64, 0, stream>>>(totals, chunkoff);
    k_scan3<<<(NN + 255) / 256, 256, 0, stream>>>(incl, deg, chunkoff, rowstart);
    k_scatter<<<(TE + 255) / 256, 256, 0, stream>>>(ei, rank, rowstart, ssrc);
    k_filldst<<<(NN + 255) / 256, 256, 0, stream>>>(rowstart, sdst);

    // bf16 prep
    int n4x = NN * INC / 4;
    k_cast4<<<(n4x + 255) / 256, 256, 0, stream>>>(x, xb, n4x);
    k_prep_w<<<256, 256, 0, stream>>>(W1l, W1r, b1l, b1r, Wt1, biasf1, 256, 128);
    k_prep_w<<<128, 128, 0, stream>>>(W2l, W2r, b2l, b2r, Wt2, biasf2, 128, 64);

    int eb = (TE + 63) / 64;

    // layer 1
    dim3 gg1((NN + 127) / 128, 2);
    k_gemm_mfma<256, 256><<<gg1, 256, 0, stream>>>(xb, Wt1, biasf1, xlr1, NN);
    k_edge<256, 4, 2><<<eb, 256, 0, stream>>>(xlr1, ssrc, sdst, att1, spk1);
    k_aggr1<<<(NN + 3) / 4, 256, 0, stream>>>(xlr1, spk1, rowstart, bias1,
                                              bn1g, bn1b, bn1m, bn1v, h1b);

    // layer 2 (+classifier)
    dim3 gg2((NN + 127) / 128, 1);
    k_gemm_mfma<128, 128><<<gg2, 256, 0, stream>>>(h1b, Wt2, biasf2, xlr2, NN);
    k_edge<128, 2, 1><<<eb, 256, 0, stream>>>(xlr2, ssrc, sdst, att2, spk2);
    k_aggr2<<<(NN + 7) / 8, 256, 0, stream>>>(xlr2, spk2, rowstart, bias2,
                                              bn2g, bn2b, bn2m, bn2v, Wc, bc, out);
}

// Round 9
// 322.369 us; speedup vs baseline: 1.3958x; 1.1042x over previous
//
#include <hip/hip_runtime.h>
#include <hip/hip_bf16.h>
#include <cstddef>

#define NN 50000
#define EE 800000
#define TE 850000   // EE + NN self loops
#define INC 256
#define C1 128      // heads(2) * hid(64)
#define C2 64
#define NCHUNK 49   // ceil(NN/1024)

typedef unsigned short ushort_t;
typedef short bf16x8 __attribute__((ext_vector_type(8)));
typedef float f32x4 __attribute__((ext_vector_type(4)));

__device__ inline ushort_t bf16r(float f) {  // RNE float->bf16
    unsigned u = __float_as_uint(f);
    unsigned r = (u + 0x7fffu + ((u >> 16) & 1u)) >> 16;
    return (ushort_t)r;
}
#define LOF(u) (__uint_as_float((u) << 16))           // low bf16 of packed uint
#define HIF(u) (__uint_as_float((u) & 0xffff0000u))   // high bf16 of packed uint
#define LRELU(t) (fmaxf((t), 0.f) + 0.2f * fminf((t), 0.f))
#define ELU(t) ((t) > 0.f ? (t) : (__expf(t) - 1.f))

// ---------------- CSR build ----------------

__global__ void k_zero(int* p, int n) {
    int i = blockIdx.x * blockDim.x + threadIdx.x;
    if (i < n) p[i] = 0;
}

// count + per-edge rank within its dst bucket (rank write is coalesced)
__global__ void k_count(const int* __restrict__ ei, int* __restrict__ deg,
                        int* __restrict__ rank) {
    int e = blockIdx.x * blockDim.x + threadIdx.x;
    if (e >= TE) return;
    int dst = (e < EE) ? ei[EE + e] : (e - EE);
    rank[e] = atomicAdd(&deg[dst], 1);
}

__global__ void k_scan1(const int* __restrict__ deg, int* __restrict__ incl,
                        int* __restrict__ totals) {
    __shared__ int lds[1024];
    int t = threadIdx.x;
    int i = blockIdx.x * 1024 + t;
    int v = (i < NN) ? deg[i] : 0;
    lds[t] = v;
    __syncthreads();
    for (int off = 1; off < 1024; off <<= 1) {
        int add = (t >= off) ? lds[t - off] : 0;
        __syncthreads();
        lds[t] += add;
        __syncthreads();
    }
    if (i < NN) incl[i] = lds[t];
    if (t == 1023) totals[blockIdx.x] = lds[t];
}

__global__ void k_scan2(const int* __restrict__ totals, int* __restrict__ chunkoff) {
    int t = threadIdx.x;
    int orig = (t < NCHUNK) ? totals[t] : 0;
    int v = orig;
    for (int off = 1; off < 64; off <<= 1) {
        int u = __shfl_up(v, off, 64);
        if (t >= off) v += u;
    }
    if (t < NCHUNK) chunkoff[t] = v - orig;
}

__global__ void k_scan3(const int* __restrict__ incl, const int* __restrict__ deg,
                        const int* __restrict__ chunkoff, int* __restrict__ rowstart) {
    int i = blockIdx.x * blockDim.x + threadIdx.x;
    if (i == 0) rowstart[NN] = TE;
    if (i >= NN) return;
    rowstart[i] = incl[i] - deg[i] + chunkoff[i >> 10];
}

// atomic-free scatter: ONE independent 4B random store per edge
__global__ void k_scatter(const int* __restrict__ ei, const int* __restrict__ rank,
                          const int* __restrict__ rowstart, int* __restrict__ ssrc) {
    int e = blockIdx.x * blockDim.x + threadIdx.x;
    if (e >= TE) return;
    int s, d;
    if (e < EE) { s = ei[e]; d = ei[EE + e]; }
    else        { s = e - EE; d = s; }
    ssrc[rowstart[d] + rank[e]] = s;
}

// ---------------- casts / weight prep ----------------

__global__ void k_cast4(const float* __restrict__ src, ushort_t* __restrict__ dst, int n4) {
    int i = blockIdx.x * blockDim.x + threadIdx.x;
    if (i >= n4) return;
    float4 a = ((const float4*)src)[i];
    ushort4 o;
    o.x = bf16r(a.x); o.y = bf16r(a.y); o.z = bf16r(a.z); o.w = bf16r(a.w);
    ((ushort4*)dst)[i] = o;
}

__global__ void k_prep_w(const float* __restrict__ Wl, const float* __restrict__ Wr,
                         const float* __restrict__ bl, const float* __restrict__ br,
                         ushort_t* __restrict__ Wt, float* __restrict__ biasf,
                         int K, int HALF) {
    int n = blockIdx.x;
    int k = threadIdx.x;
    const float* W = (n < HALF) ? Wl : Wr;
    int c = (n < HALF) ? n : n - HALF;
    Wt[(size_t)n * K + k] = bf16r(W[(size_t)k * HALF + c]);
    if (n == 0 && k < 2 * HALF) biasf[k] = (k < HALF) ? bl[k] : br[k - HALF];
}

// ---------------- bf16 MFMA GEMM ----------------
// C[M,NCOL](bf16) = A[M,K](bf16) @ Bt[NCOL,K]^T + bias(fp32)
// 128x128 tile, BK=32, 256 threads, 16x16x32 MFMA; LDS rows padded to 40 bf16.

template <int K, int NCOL>
__global__ __launch_bounds__(256) void k_gemm_mfma(const ushort_t* __restrict__ A,
                                                   const ushort_t* __restrict__ Bt,
                                                   const float* __restrict__ bias,
                                                   ushort_t* __restrict__ C, int M) {
    __shared__ __align__(16) ushort_t As[128 * 40];
    __shared__ __align__(16) ushort_t Bs[128 * 40];
    int tid = threadIdx.x;
    int bm = blockIdx.x * 128;
    int bn = blockIdx.y * 128;
    int w = tid >> 6, l = tid & 63;
    int wm = (w & 1) * 64, wn = (w >> 1) * 64;
    int lm = l & 15, half = l >> 4;

    f32x4 zero = {0.f, 0.f, 0.f, 0.f};
    f32x4 acc[4][4];
#pragma unroll
    for (int a = 0; a < 4; a++)
#pragma unroll
        for (int b = 0; b < 4; b++) acc[a][b] = zero;

    for (int k0 = 0; k0 < K; k0 += 32) {
#pragma unroll
        for (int q = 0; q < 2; q++) {
            int seg = q * 256 + tid;
            int m = seg >> 2;
            int ko = (seg & 3) * 8;
            *(float4*)&As[m * 40 + ko] = *(const float4*)&A[(size_t)(bm + m) * K + k0 + ko];
            *(float4*)&Bs[m * 40 + ko] = *(const float4*)&Bt[(size_t)(bn + m) * K + k0 + ko];
        }
        __syncthreads();
        bf16x8 af[4], bfr[4];
#pragma unroll
        for (int mi = 0; mi < 4; mi++)
            af[mi] = *(const bf16x8*)&As[(wm + mi * 16 + lm) * 40 + half * 8];
#pragma unroll
        for (int ni = 0; ni < 4; ni++)
            bfr[ni] = *(const bf16x8*)&Bs[(wn + ni * 16 + lm) * 40 + half * 8];
#pragma unroll
        for (int mi = 0; mi < 4; mi++)
#pragma unroll
            for (int ni = 0; ni < 4; ni++)
                acc[mi][ni] = __builtin_amdgcn_mfma_f32_16x16x32_bf16(
                    af[mi], bfr[ni], acc[mi][ni], 0, 0, 0);
        __syncthreads();
    }
#pragma unroll
    for (int ni = 0; ni < 4; ni++) {
        int col = bn + wn + ni * 16 + lm;
        float bv = bias[col];
#pragma unroll
        for (int mi = 0; mi < 4; mi++) {
            int rbase = bm + wm + mi * 16 + half * 4;
#pragma unroll
            for (int r = 0; r < 4; r++) {
                int row = rbase + r;
                if (row < M) C[(size_t)row * NCOL + col] = bf16r(acc[mi][ni][r] + bv);
            }
        }
    }
}

// ---------------- Fused GATv2 layer (logit + softmax + aggregate + epilogue) ----------------
// Layer 1: one wave per node; lane covers 4 channels (c2=lane&31 -> ch 4*c2..4*c2+3,
// head = c2>>4); half-wave hw is an edge slot (edges row+2k+hw). Per edge: gather
// xl[src] (uint2/lane = 256 B/half-wave... full row via 32 lanes), 4-ch dot partial,
// butterfly xor{1,2,4,8} (within 16-lane head group; one instr serves both half-waves),
// exp, FMA p*xl from the same registers. xr + att loaded once per node.

__global__ __launch_bounds__(256) void k_fused1(
    const ushort_t* __restrict__ xlr, const int* __restrict__ rowstart,
    const int* __restrict__ ssrc, const float* __restrict__ att,
    const float* __restrict__ bias,
    const float* __restrict__ g, const float* __restrict__ b,
    const float* __restrict__ m, const float* __restrict__ v,
    ushort_t* __restrict__ out) {
    int lane = threadIdx.x & 63;
    int i = blockIdx.x * 4 + (threadIdx.x >> 6);
    if (i >= NN) return;
    int hw = lane >> 5;
    int c2 = lane & 31;
    uint2 xru = *(const uint2*)&xlr[(size_t)i * 256 + 128 + 4 * c2];
    float xr0 = LOF(xru.x), xr1 = HIF(xru.x), xr2 = LOF(xru.y), xr3 = HIF(xru.y);
    float4 at = *(const float4*)&att[4 * c2];
    int row = rowstart[i], end = rowstart[i + 1];
    float a0 = 0.f, a1 = 0.f, a2 = 0.f, a3 = 0.f, s = 0.f;
    int j = row;
    for (; j + 8 <= end; j += 8) {
        int src[4];
        uint2 u[4];
#pragma unroll
        for (int k = 0; k < 4; k++) src[k] = ssrc[j + 2 * k + hw];
#pragma unroll
        for (int k = 0; k < 4; k++)
            u[k] = *(const uint2*)&xlr[(size_t)src[k] * 256 + 4 * c2];
        float d[4], f0[4], f1[4], f2[4], f3[4];
#pragma unroll
        for (int k = 0; k < 4; k++) {
            f0[k] = LOF(u[k].x); f1[k] = HIF(u[k].x);
            f2[k] = LOF(u[k].y); f3[k] = HIF(u[k].y);
            float t0 = f0[k] + xr0, t1 = f1[k] + xr1;
            float t2 = f2[k] + xr2, t3 = f3[k] + xr3;
            d[k] = at.x * LRELU(t0) + at.y * LRELU(t1)
                 + at.z * LRELU(t2) + at.w * LRELU(t3);
        }
#pragma unroll
        for (int o = 1; o <= 8; o <<= 1) {
#pragma unroll
            for (int k = 0; k < 4; k++) d[k] += __shfl_xor(d[k], o, 64);
        }
#pragma unroll
        for (int k = 0; k < 4; k++) {
            float p = __expf(d[k]);
            a0 += p * f0[k]; a1 += p * f1[k];
            a2 += p * f2[k]; a3 += p * f3[k];
            s += p;
        }
    }
    for (; j < end; j += 2) {
        int je = j + hw;
        bool valid = je < end;
        int src = valid ? ssrc[je] : i;
        uint2 uu = *(const uint2*)&xlr[(size_t)src * 256 + 4 * c2];
        float f0 = LOF(uu.x), f1 = HIF(uu.x), f2 = LOF(uu.y), f3 = HIF(uu.y);
        float t0 = f0 + xr0, t1 = f1 + xr1, t2 = f2 + xr2, t3 = f3 + xr3;
        float d = at.x * LRELU(t0) + at.y * LRELU(t1)
                + at.z * LRELU(t2) + at.w * LRELU(t3);
        d += __shfl_xor(d, 1, 64);
        d += __shfl_xor(d, 2, 64);
        d += __shfl_xor(d, 4, 64);
        d += __shfl_xor(d, 8, 64);
        float p = valid ? __expf(d) : 0.f;
        a0 += p * f0; a1 += p * f1; a2 += p * f2; a3 += p * f3;
        s += p;
    }
    // combine the two half-wave edge slots (channels replicated across hw)
    a0 += __shfl_xor(a0, 32, 64);
    a1 += __shfl_xor(a1, 32, 64);
    a2 += __shfl_xor(a2, 32, 64);
    a3 += __shfl_xor(a3, 32, 64);
    s  += __shfl_xor(s, 32, 64);
    if (hw == 0) {
        float inv = 1.f / s;
        float4 bb = *(const float4*)&bias[4 * c2];
        float4 mm = *(const float4*)&m[4 * c2];
        float4 vv = *(const float4*)&v[4 * c2];
        float4 gg = *(const float4*)&g[4 * c2];
        float4 b2 = *(const float4*)&b[4 * c2];
        float o0 = a0 * inv + bb.x, o1 = a1 * inv + bb.y;
        float o2 = a2 * inv + bb.z, o3 = a3 * inv + bb.w;
        o0 = (o0 - mm.x) * rsqrtf(vv.x + 1e-5f) * gg.x + b2.x;
        o1 = (o1 - mm.y) * rsqrtf(vv.y + 1e-5f) * gg.y + b2.y;
        o2 = (o2 - mm.z) * rsqrtf(vv.z + 1e-5f) * gg.z + b2.z;
        o3 = (o3 - mm.w) * rsqrtf(vv.w + 1e-5f) * gg.w + b2.w;
        o0 = ELU(o0); o1 = ELU(o1); o2 = ELU(o2); o3 = ELU(o3);
        uint2 wp;
        wp.x = (unsigned)bf16r(o0) | ((unsigned)bf16r(o1) << 16);
        wp.y = (unsigned)bf16r(o2) | ((unsigned)bf16r(o3) << 16);
        *(uint2*)&out[(size_t)i * C1 + 4 * c2] = wp;
    }
}

// Layer 2 + classifier: one wave per node; lane covers 4 of 64 channels (c4=lane&15),
// quarter-wave qw is an edge slot (edges row+4k+qw) -> 4 edges in flight per instr.
__global__ __launch_bounds__(256) void k_fused2(
    const ushort_t* __restrict__ xlr, const int* __restrict__ rowstart,
    const int* __restrict__ ssrc, const float* __restrict__ att,
    const float* __restrict__ bias,
    const float* __restrict__ g, const float* __restrict__ b,
    const float* __restrict__ m, const float* __restrict__ v,
    const float* __restrict__ Wc, const float* __restrict__ bc,
    float* __restrict__ out) {
    int lane = threadIdx.x & 63;
    int i = blockIdx.x * 4 + (threadIdx.x >> 6);
    if (i >= NN) return;
    int qw = lane >> 4;
    int c4 = lane & 15;
    uint2 xru = *(const uint2*)&xlr[(size_t)i * 128 + 64 + 4 * c4];
    float xr0 = LOF(xru.x), xr1 = HIF(xru.x), xr2 = LOF(xru.y), xr3 = HIF(xru.y);
    float4 at = *(const float4*)&att[4 * c4];
    int row = rowstart[i], end = rowstart[i + 1];
    float a0 = 0.f, a1 = 0.f, a2 = 0.f, a3 = 0.f, s = 0.f;
    int j = row;
    for (; j + 8 <= end; j += 8) {
        int src[2];
        uint2 u[2];
#pragma unroll
        for (int k = 0; k < 2; k++) src[k] = ssrc[j + 4 * k + qw];
#pragma unroll
        for (int k = 0; k < 2; k++)
            u[k] = *(const uint2*)&xlr[(size_t)src[k] * 128 + 4 * c4];
        float d[2], f0[2], f1[2], f2[2], f3[2];
#pragma unroll
        for (int k = 0; k < 2; k++) {
            f0[k] = LOF(u[k].x); f1[k] = HIF(u[k].x);
            f2[k] = LOF(u[k].y); f3[k] = HIF(u[k].y);
            float t0 = f0[k] + xr0, t1 = f1[k] + xr1;
            float t2 = f2[k] + xr2, t3 = f3[k] + xr3;
            d[k] = at.x * LRELU(t0) + at.y * LRELU(t1)
                 + at.z * LRELU(t2) + at.w * LRELU(t3);
        }
#pragma unroll
        for (int o = 1; o <= 8; o <<= 1) {
#pragma unroll
            for (int k = 0; k < 2; k++) d[k] += __shfl_xor(d[k], o, 64);
        }
#pragma unroll
        for (int k = 0; k < 2; k++) {
            float p = __expf(d[k]);
            a0 += p * f0[k]; a1 += p * f1[k];
            a2 += p * f2[k]; a3 += p * f3[k];
            s += p;
        }
    }
    for (; j < end; j += 4) {
        int je = j + qw;
        bool valid = je < end;
        int src = valid ? ssrc[je] : i;
        uint2 uu = *(const uint2*)&xlr[(size_t)src * 128 + 4 * c4];
        float f0 = LOF(uu.x), f1 = HIF(uu.x), f2 = LOF(uu.y), f3 = HIF(uu.y);
        float t0 = f0 + xr0, t1 = f1 + xr1, t2 = f2 + xr2, t3 = f3 + xr3;
        float d = at.x * LRELU(t0) + at.y * LRELU(t1)
                + at.z * LRELU(t2) + at.w * LRELU(t3);
        d += __shfl_xor(d, 1, 64);
        d += __shfl_xor(d, 2, 64);
        d += __shfl_xor(d, 4, 64);
        d += __shfl_xor(d, 8, 64);
        float p = valid ? __expf(d) : 0.f;
        a0 += p * f0; a1 += p * f1; a2 += p * f2; a3 += p * f3;
        s += p;
    }
    // combine the 4 quarter-wave edge slots
#pragma unroll
    for (int o = 16; o <= 32; o <<= 1) {
        a0 += __shfl_xor(a0, o, 64);
        a1 += __shfl_xor(a1, o, 64);
        a2 += __shfl_xor(a2, o, 64);
        a3 += __shfl_xor(a3, o, 64);
        s  += __shfl_xor(s, o, 64);
    }
    float inv = 1.f / s;
    float4 bb = *(const float4*)&bias[4 * c4];
    float4 mm = *(const float4*)&m[4 * c4];
    float4 vv = *(const float4*)&v[4 * c4];
    float4 gg = *(const float4*)&g[4 * c4];
    float4 b2 = *(const float4*)&b[4 * c4];
    float o0 = a0 * inv + bb.x, o1 = a1 * inv + bb.y;
    float o2 = a2 * inv + bb.z, o3 = a3 * inv + bb.w;
    o0 = (o0 - mm.x) * rsqrtf(vv.x + 1e-5f) * gg.x + b2.x;
    o1 = (o1 - mm.y) * rsqrtf(vv.y + 1e-5f) * gg.y + b2.y;
    o2 = (o2 - mm.z) * rsqrtf(vv.z + 1e-5f) * gg.z + b2.z;
    o3 = (o3 - mm.w) * rsqrtf(vv.w + 1e-5f) * gg.w + b2.w;
    o0 = ELU(o0); o1 = ELU(o1); o2 = ELU(o2); o3 = ELU(o3);
    float4 wc = *(const float4*)&Wc[4 * c4];
    float z = o0 * wc.x + o1 * wc.y + o2 * wc.z + o3 * wc.w;
    z += __shfl_xor(z, 1, 64);
    z += __shfl_xor(z, 2, 64);
    z += __shfl_xor(z, 4, 64);
    z += __shfl_xor(z, 8, 64);
    if (lane == 0) out[i] = 1.f / (1.f + __expf(-(z + bc[0])));
}

// ---------------- launch ----------------

extern "C" void kernel_launch(void* const* d_in, const int* in_sizes, int n_in,
                              void* d_out, int out_size, void* d_ws, size_t ws_size,
                              hipStream_t stream) {
    const float* x    = (const float*)d_in[0];
    const int*   ei   = (const int*)d_in[1];
    const float* W1l  = (const float*)d_in[2];
    const float* b1l  = (const float*)d_in[3];
    const float* W1r  = (const float*)d_in[4];
    const float* b1r  = (const float*)d_in[5];
    const float* att1 = (const float*)d_in[6];
    const float* bias1= (const float*)d_in[7];
    const float* bn1g = (const float*)d_in[8];
    const float* bn1b = (const float*)d_in[9];
    const float* bn1m = (const float*)d_in[10];
    const float* bn1v = (const float*)d_in[11];
    const float* W2l  = (const float*)d_in[12];
    const float* b2l  = (const float*)d_in[13];
    const float* W2r  = (const float*)d_in[14];
    const float* b2r  = (const float*)d_in[15];
    const float* att2 = (const float*)d_in[16];
    const float* bias2= (const float*)d_in[17];
    const float* bn2g = (const float*)d_in[18];
    const float* bn2b = (const float*)d_in[19];
    const float* bn2m = (const float*)d_in[20];
    const float* bn2v = (const float*)d_in[21];
    const float* Wc   = (const float*)d_in[22];
    const float* bc   = (const float*)d_in[23];
    float* out = (float*)d_out;

    char* ws = (char*)d_ws;
    size_t off = 0;
    auto alloc = [&](size_t bytes) {
        size_t o = off;
        off += (bytes + 255) & ~(size_t)255;
        return o;
    };
    ushort_t* xb    = (ushort_t*)(ws + alloc((size_t)(NN + 128) * 256 * 2));
    ushort_t* xlr1  = (ushort_t*)(ws + alloc((size_t)NN * 256 * 2));  // reused as xlr2
    ushort_t* h1b   = (ushort_t*)(ws + alloc((size_t)(NN + 128) * 128 * 2));
    ushort_t* Wt1   = (ushort_t*)(ws + alloc((size_t)256 * 256 * 2));
    float*    biasf1= (float*)(ws + alloc(256 * 4));
    ushort_t* Wt2   = (ushort_t*)(ws + alloc((size_t)128 * 128 * 2));
    float*    biasf2= (float*)(ws + alloc(128 * 4));
    int* deg      = (int*)(ws + alloc((size_t)NN * 4));
    int* incl     = (int*)(ws + alloc((size_t)NN * 4));
    int* rowstart = (int*)(ws + alloc((size_t)(NN + 1) * 4));
    int* totals   = (int*)(ws + alloc(64 * 4));
    int* chunkoff = (int*)(ws + alloc(64 * 4));
    int* rank     = (int*)(ws + alloc((size_t)TE * 4));
    int* ssrc     = (int*)(ws + alloc((size_t)TE * 4));
    ushort_t* xlr2 = xlr1;

    // CSR build: one atomic pass (count+rank), scan, atomic-free scatter
    k_zero<<<(NN + 255) / 256, 256, 0, stream>>>(deg, NN);
    k_count<<<(TE + 255) / 256, 256, 0, stream>>>(ei, deg, rank);
    k_scan1<<<NCHUNK, 1024, 0, stream>>>(deg, incl, totals);
    k_scan2<<<1, 64, 0, stream>>>(totals, chunkoff);
    k_scan3<<<(NN + 255) / 256, 256, 0, stream>>>(incl, deg, chunkoff, rowstart);
    k_scatter<<<(TE + 255) / 256, 256, 0, stream>>>(ei, rank, rowstart, ssrc);

    // bf16 prep
    int n4x = NN * INC / 4;
    k_cast4<<<(n4x + 255) / 256, 256, 0, stream>>>(x, xb, n4x);
    k_prep_w<<<256, 256, 0, stream>>>(W1l, W1r, b1l, b1r, Wt1, biasf1, 256, 128);
    k_prep_w<<<128, 128, 0, stream>>>(W2l, W2r, b2l, b2r, Wt2, biasf2, 128, 64);

    // layer 1
    dim3 gg1((NN + 127) / 128, 2);
    k_gemm_mfma<256, 256><<<gg1, 256, 0, stream>>>(xb, Wt1, biasf1, xlr1, NN);
    k_fused1<<<(NN + 3) / 4, 256, 0, stream>>>(xlr1, rowstart, ssrc, att1, bias1,
                                               bn1g, bn1b, bn1m, bn1v, h1b);

    // layer 2 (+classifier)
    dim3 gg2((NN + 127) / 128, 1);
    k_gemm_mfma<128, 128><<<gg2, 256, 0, stream>>>(h1b, Wt2, biasf2, xlr2, NN);
    k_fused2<<<(NN + 3) / 4, 256, 0, stream>>>(xlr2, rowstart, ssrc, att2, bias2,
                                               bn2g, bn2b, bn2m, bn2v, Wc, bc, out);
}

// Round 11
// 307.232 us; speedup vs baseline: 1.4646x; 1.0493x over previous
//
#include <hip/hip_runtime.h>
#include <hip/hip_bf16.h>
#include <cstddef>

#define NN 50000
#define EE 800000
#define TE 850000   // EE + NN self loops
#define INC 256
#define C1 128      // heads(2) * hid(64)
#define C2 64
#define NCHUNK 49   // ceil(NN/1024)

// block-range dispatch for merged kernels
#define NB_COUNT 3321   // ceil(TE/256)
#define NB_CAST  12500  // NN*INC elements / 4 per thread / 256 threads
#define NB_P1    256
#define NB_P2    128
#define NB_K1    (NB_COUNT + NB_CAST + NB_P1 + NB_P2)
#define NB_GEMM1 782    // 391*2 (128x128 tiles over 50000x256)
#define NB_K2    (NB_GEMM1 + NB_COUNT)

typedef unsigned short ushort_t;
typedef short bf16x8 __attribute__((ext_vector_type(8)));
typedef float f32x4 __attribute__((ext_vector_type(4)));

__device__ inline ushort_t bf16r(float f) {  // RNE float->bf16
    unsigned u = __float_as_uint(f);
    unsigned r = (u + 0x7fffu + ((u >> 16) & 1u)) >> 16;
    return (ushort_t)r;
}
#define LOF(u) (__uint_as_float((u) << 16))           // low bf16 of packed uint
#define HIF(u) (__uint_as_float((u) & 0xffff0000u))   // high bf16 of packed uint
#define LRELU(t) (fmaxf((t), 0.f) + 0.2f * fminf((t), 0.f))
#define ELU(t) ((t) > 0.f ? (t) : (__expf(t) - 1.f))

// ---------------- scans (serial dependency, small) ----------------

__global__ void k_scan1(const int* __restrict__ deg, int* __restrict__ incl,
                        int* __restrict__ totals) {
    __shared__ int lds[1024];
    int t = threadIdx.x;
    int i = blockIdx.x * 1024 + t;
    int v = (i < NN) ? deg[i] : 0;
    lds[t] = v;
    __syncthreads();
    for (int off = 1; off < 1024; off <<= 1) {
        int add = (t >= off) ? lds[t - off] : 0;
        __syncthreads();
        lds[t] += add;
        __syncthreads();
    }
    if (i < NN) incl[i] = lds[t];
    if (t == 1023) totals[blockIdx.x] = lds[t];
}

__global__ void k_scan2(const int* __restrict__ totals, int* __restrict__ chunkoff) {
    int t = threadIdx.x;
    int orig = (t < NCHUNK) ? totals[t] : 0;
    int v = orig;
    for (int off = 1; off < 64; off <<= 1) {
        int u = __shfl_up(v, off, 64);
        if (t >= off) v += u;
    }
    if (t < NCHUNK) chunkoff[t] = v - orig;
}

__global__ void k_scan3(const int* __restrict__ incl, const int* __restrict__ deg,
                        const int* __restrict__ chunkoff, int* __restrict__ rowstart) {
    int i = blockIdx.x * blockDim.x + threadIdx.x;
    if (i == 0) rowstart[NN] = TE;
    if (i >= NN) return;
    rowstart[i] = incl[i] - deg[i] + chunkoff[i >> 10];
}

// ---------------- K1: count+rank | cast | prep_w1 | prep_w2 (independent stages) ----------------

__global__ __launch_bounds__(256) void k_stage1(
    const int* __restrict__ ei, int* __restrict__ deg, int* __restrict__ rank,
    const float* __restrict__ x, ushort_t* __restrict__ xb,
    const float* __restrict__ W1l, const float* __restrict__ W1r,
    const float* __restrict__ b1l, const float* __restrict__ b1r,
    ushort_t* __restrict__ Wt1, float* __restrict__ biasf1,
    const float* __restrict__ W2l, const float* __restrict__ W2r,
    const float* __restrict__ b2l, const float* __restrict__ b2r,
    ushort_t* __restrict__ Wt2, float* __restrict__ biasf2) {
    int b = blockIdx.x;
    int tid = threadIdx.x;
    if (b < NB_COUNT) {
        // count + per-edge rank (rank write coalesced)
        int e = b * 256 + tid;
        if (e < TE) {
            int dst = (e < EE) ? ei[EE + e] : (e - EE);
            rank[e] = atomicAdd(&deg[dst], 1);
        }
    } else if (b < NB_COUNT + NB_CAST) {
        // fp32 -> bf16 cast of x, one float4 (4 elements) per thread
        int i = (b - NB_COUNT) * 256 + tid;  // i < 3,200,000 float4's
        float4 a = ((const float4*)x)[i];
        ushort4 o;
        o.x = bf16r(a.x); o.y = bf16r(a.y); o.z = bf16r(a.z); o.w = bf16r(a.w);
        ((ushort4*)xb)[i] = o;
    } else if (b < NB_COUNT + NB_CAST + NB_P1) {
        // prep W1: Wt1[n][k], n in [0,256), K=256, HALF=128
        int n = b - NB_COUNT - NB_CAST;
        int k = tid;
        const float* W = (n < 128) ? W1l : W1r;
        int c = (n < 128) ? n : n - 128;
        Wt1[(size_t)n * 256 + k] = bf16r(W[(size_t)k * 128 + c]);
        if (n == 0) biasf1[k] = (k < 128) ? b1l[k] : b1r[k - 128];
    } else {
        // prep W2: Wt2[n][k], n in [0,128), K=128, HALF=64
        int n = b - NB_COUNT - NB_CAST - NB_P1;
        int k = tid;
        if (k < 128) {
            const float* W = (n < 64) ? W2l : W2r;
            int c = (n < 64) ? n : n - 64;
            Wt2[(size_t)n * 128 + k] = bf16r(W[(size_t)k * 64 + c]);
            if (n == 0) biasf2[k] = (k < 64) ? b2l[k] : b2r[k - 64];
        }
    }
}

// ---------------- bf16 MFMA GEMM body (shared by K2 and gemm2) ----------------
// C[M,NCOL](bf16) = A[M,K](bf16) @ Bt[NCOL,K]^T + bias(fp32)
// 128x128 tile, BK=32, 256 threads, 16x16x32 MFMA; LDS rows padded to 40 bf16.

template <int K, int NCOL>
__device__ inline void gemm_body(const ushort_t* __restrict__ A,
                                 const ushort_t* __restrict__ Bt,
                                 const float* __restrict__ bias,
                                 ushort_t* __restrict__ C, int M,
                                 int bm, int bn, ushort_t* As, ushort_t* Bs) {
    int tid = threadIdx.x;
    int w = tid >> 6, l = tid & 63;
    int wm = (w & 1) * 64, wn = (w >> 1) * 64;
    int lm = l & 15, half = l >> 4;

    f32x4 zero = {0.f, 0.f, 0.f, 0.f};
    f32x4 acc[4][4];
#pragma unroll
    for (int a = 0; a < 4; a++)
#pragma unroll
        for (int b = 0; b < 4; b++) acc[a][b] = zero;

    for (int k0 = 0; k0 < K; k0 += 32) {
#pragma unroll
        for (int q = 0; q < 2; q++) {
            int seg = q * 256 + tid;
            int m = seg >> 2;
            int ko = (seg & 3) * 8;
            *(float4*)&As[m * 40 + ko] = *(const float4*)&A[(size_t)(bm + m) * K + k0 + ko];
            *(float4*)&Bs[m * 40 + ko] = *(const float4*)&Bt[(size_t)(bn + m) * K + k0 + ko];
        }
        __syncthreads();
        bf16x8 af[4], bfr[4];
#pragma unroll
        for (int mi = 0; mi < 4; mi++)
            af[mi] = *(const bf16x8*)&As[(wm + mi * 16 + lm) * 40 + half * 8];
#pragma unroll
        for (int ni = 0; ni < 4; ni++)
            bfr[ni] = *(const bf16x8*)&Bs[(wn + ni * 16 + lm) * 40 + half * 8];
#pragma unroll
        for (int mi = 0; mi < 4; mi++)
#pragma unroll
            for (int ni = 0; ni < 4; ni++)
                acc[mi][ni] = __builtin_amdgcn_mfma_f32_16x16x32_bf16(
                    af[mi], bfr[ni], acc[mi][ni], 0, 0, 0);
        __syncthreads();
    }
#pragma unroll
    for (int ni = 0; ni < 4; ni++) {
        int col = bn + wn + ni * 16 + lm;
        float bv = bias[col];
#pragma unroll
        for (int mi = 0; mi < 4; mi++) {
            int rbase = bm + wm + mi * 16 + half * 4;
#pragma unroll
            for (int r = 0; r < 4; r++) {
                int row = rbase + r;
                if (row < M) C[(size_t)row * NCOL + col] = bf16r(acc[mi][ni][r] + bv);
            }
        }
    }
}

// ---------------- K2: GEMM layer-1 | scatter (independent) ----------------
// GEMM blocks first so they grab the CUs; latency-bound scatter blocks hide under them.

__global__ __launch_bounds__(256) void k_gemm1_scatter(
    const ushort_t* __restrict__ A, const ushort_t* __restrict__ Bt,
    const float* __restrict__ bias, ushort_t* __restrict__ C,
    const int* __restrict__ ei, const int* __restrict__ rank,
    const int* __restrict__ rowstart, int* __restrict__ ssrc) {
    __shared__ __align__(16) ushort_t As[128 * 40];
    __shared__ __align__(16) ushort_t Bs[128 * 40];
    int b = blockIdx.x;
    if (b < NB_GEMM1) {
        int bm = (b >> 1) * 128;
        int bn = (b & 1) * 128;
        gemm_body<256, 256>(A, Bt, bias, C, NN, bm, bn, As, Bs);
    } else {
        // atomic-free scatter: one independent 4B random store per edge
        int e = (b - NB_GEMM1) * 256 + threadIdx.x;
        if (e < TE) {
            int s, d;
            if (e < EE) { s = ei[e]; d = ei[EE + e]; }
            else        { s = e - EE; d = s; }
            ssrc[rowstart[d] + rank[e]] = s;
        }
    }
}

__global__ __launch_bounds__(256) void k_gemm2(
    const ushort_t* __restrict__ A, const ushort_t* __restrict__ Bt,
    const float* __restrict__ bias, ushort_t* __restrict__ C) {
    __shared__ __align__(16) ushort_t As[128 * 40];
    __shared__ __align__(16) ushort_t Bs[128 * 40];
    int bm = blockIdx.x * 128;
    gemm_body<128, 128>(A, Bt, bias, C, NN, bm, 0, As, Bs);
}

// ---------------- Fused GATv2 layer (logit + softmax + aggregate + epilogue) ----------------
// Layer 1: one wave per node; lane covers 4 channels (c2=lane&31, head=c2>>4);
// half-wave hw is an edge slot. Butterfly xor{1,2,4,8} sums each head's 16-lane group.

__global__ __launch_bounds__(256) void k_fused1(
    const ushort_t* __restrict__ xlr, const int* __restrict__ rowstart,
    const int* __restrict__ ssrc, const float* __restrict__ att,
    const float* __restrict__ bias,
    const float* __restrict__ g, const float* __restrict__ b,
    const float* __restrict__ m, const float* __restrict__ v,
    ushort_t* __restrict__ out) {
    int lane = threadIdx.x & 63;
    int i = blockIdx.x * 4 + (threadIdx.x >> 6);
    if (i >= NN) return;
    int hw = lane >> 5;
    int c2 = lane & 31;
    uint2 xru = *(const uint2*)&xlr[(size_t)i * 256 + 128 + 4 * c2];
    float xr0 = LOF(xru.x), xr1 = HIF(xru.x), xr2 = LOF(xru.y), xr3 = HIF(xru.y);
    float4 at = *(const float4*)&att[4 * c2];
    int row = rowstart[i], end = rowstart[i + 1];
    float a0 = 0.f, a1 = 0.f, a2 = 0.f, a3 = 0.f, s = 0.f;
    int j = row;
    for (; j + 8 <= end; j += 8) {
        int src[4];
        uint2 u[4];
#pragma unroll
        for (int k = 0; k < 4; k++) src[k] = ssrc[j + 2 * k + hw];
#pragma unroll
        for (int k = 0; k < 4; k++)
            u[k] = *(const uint2*)&xlr[(size_t)src[k] * 256 + 4 * c2];
        float d[4], f0[4], f1[4], f2[4], f3[4];
#pragma unroll
        for (int k = 0; k < 4; k++) {
            f0[k] = LOF(u[k].x); f1[k] = HIF(u[k].x);
            f2[k] = LOF(u[k].y); f3[k] = HIF(u[k].y);
            float t0 = f0[k] + xr0, t1 = f1[k] + xr1;
            float t2 = f2[k] + xr2, t3 = f3[k] + xr3;
            d[k] = at.x * LRELU(t0) + at.y * LRELU(t1)
                 + at.z * LRELU(t2) + at.w * LRELU(t3);
        }
#pragma unroll
        for (int o = 1; o <= 8; o <<= 1) {
#pragma unroll
            for (int k = 0; k < 4; k++) d[k] += __shfl_xor(d[k], o, 64);
        }
#pragma unroll
        for (int k = 0; k < 4; k++) {
            float p = __expf(d[k]);
            a0 += p * f0[k]; a1 += p * f1[k];
            a2 += p * f2[k]; a3 += p * f3[k];
            s += p;
        }
    }
    for (; j < end; j += 2) {
        int je = j + hw;
        bool valid = je < end;
        int src = valid ? ssrc[je] : i;
        uint2 uu = *(const uint2*)&xlr[(size_t)src * 256 + 4 * c2];
        float f0 = LOF(uu.x), f1 = HIF(uu.x), f2 = LOF(uu.y), f3 = HIF(uu.y);
        float t0 = f0 + xr0, t1 = f1 + xr1, t2 = f2 + xr2, t3 = f3 + xr3;
        float d = at.x * LRELU(t0) + at.y * LRELU(t1)
                + at.z * LRELU(t2) + at.w * LRELU(t3);
        d += __shfl_xor(d, 1, 64);
        d += __shfl_xor(d, 2, 64);
        d += __shfl_xor(d, 4, 64);
        d += __shfl_xor(d, 8, 64);
        float p = valid ? __expf(d) : 0.f;
        a0 += p * f0; a1 += p * f1; a2 += p * f2; a3 += p * f3;
        s += p;
    }
    // combine the two half-wave edge slots (channels replicated across hw)
    a0 += __shfl_xor(a0, 32, 64);
    a1 += __shfl_xor(a1, 32, 64);
    a2 += __shfl_xor(a2, 32, 64);
    a3 += __shfl_xor(a3, 32, 64);
    s  += __shfl_xor(s, 32, 64);
    if (hw == 0) {
        float inv = 1.f / s;
        float4 bb = *(const float4*)&bias[4 * c2];
        float4 mm = *(const float4*)&m[4 * c2];
        float4 vv = *(const float4*)&v[4 * c2];
        float4 gg = *(const float4*)&g[4 * c2];
        float4 b2 = *(const float4*)&b[4 * c2];
        float o0 = a0 * inv + bb.x, o1 = a1 * inv + bb.y;
        float o2 = a2 * inv + bb.z, o3 = a3 * inv + bb.w;
        o0 = (o0 - mm.x) * rsqrtf(vv.x + 1e-5f) * gg.x + b2.x;
        o1 = (o1 - mm.y) * rsqrtf(vv.y + 1e-5f) * gg.y + b2.y;
        o2 = (o2 - mm.z) * rsqrtf(vv.z + 1e-5f) * gg.z + b2.z;
        o3 = (o3 - mm.w) * rsqrtf(vv.w + 1e-5f) * gg.w + b2.w;
        o0 = ELU(o0); o1 = ELU(o1); o2 = ELU(o2); o3 = ELU(o3);
        uint2 wp;
        wp.x = (unsigned)bf16r(o0) | ((unsigned)bf16r(o1) << 16);
        wp.y = (unsigned)bf16r(o2) | ((unsigned)bf16r(o3) << 16);
        *(uint2*)&out[(size_t)i * C1 + 4 * c2] = wp;
    }
}

// Layer 2 + classifier: one wave per node; lane covers 4 of 64 channels (c4=lane&15),
// quarter-wave qw is an edge slot -> 4 edges in flight per instr.
__global__ __launch_bounds__(256) void k_fused2(
    const ushort_t* __restrict__ xlr, const int* __restrict__ rowstart,
    const int* __restrict__ ssrc, const float* __restrict__ att,
    const float* __restrict__ bias,
    const float* __restrict__ g, const float* __restrict__ b,
    const float* __restrict__ m, const float* __restrict__ v,
    const float* __restrict__ Wc, const float* __restrict__ bc,
    float* __restrict__ out) {
    int lane = threadIdx.x & 63;
    int i = blockIdx.x * 4 + (threadIdx.x >> 6);
    if (i >= NN) return;
    int qw = lane >> 4;
    int c4 = lane & 15;
    uint2 xru = *(const uint2*)&xlr[(size_t)i * 128 + 64 + 4 * c4];
    float xr0 = LOF(xru.x), xr1 = HIF(xru.x), xr2 = LOF(xru.y), xr3 = HIF(xru.y);
    float4 at = *(const float4*)&att[4 * c4];
    int row = rowstart[i], end = rowstart[i + 1];
    float a0 = 0.f, a1 = 0.f, a2 = 0.f, a3 = 0.f, s = 0.f;
    int j = row;
    for (; j + 8 <= end; j += 8) {
        int src[2];
        uint2 u[2];
#pragma unroll
        for (int k = 0; k < 2; k++) src[k] = ssrc[j + 4 * k + qw];
#pragma unroll
        for (int k = 0; k < 2; k++)
            u[k] = *(const uint2*)&xlr[(size_t)src[k] * 128 + 4 * c4];
        float d[2], f0[2], f1[2], f2[2], f3[2];
#pragma unroll
        for (int k = 0; k < 2; k++) {
            f0[k] = LOF(u[k].x); f1[k] = HIF(u[k].x);
            f2[k] = LOF(u[k].y); f3[k] = HIF(u[k].y);
            float t0 = f0[k] + xr0, t1 = f1[k] + xr1;
            float t2 = f2[k] + xr2, t3 = f3[k] + xr3;
            d[k] = at.x * LRELU(t0) + at.y * LRELU(t1)
                 + at.z * LRELU(t2) + at.w * LRELU(t3);
        }
#pragma unroll
        for (int o = 1; o <= 8; o <<= 1) {
#pragma unroll
            for (int k = 0; k < 2; k++) d[k] += __shfl_xor(d[k], o, 64);
        }
#pragma unroll
        for (int k = 0; k < 2; k++) {
            float p = __expf(d[k]);
            a0 += p * f0[k]; a1 += p * f1[k];
            a2 += p * f2[k]; a3 += p * f3[k];
            s += p;
        }
    }
    for (; j < end; j += 4) {
        int je = j + qw;
        bool valid = je < end;
        int src = valid ? ssrc[je] : i;
        uint2 uu = *(const uint2*)&xlr[(size_t)src * 128 + 4 * c4];
        float f0 = LOF(uu.x), f1 = HIF(uu.x), f2 = LOF(uu.y), f3 = HIF(uu.y);
        float t0 = f0 + xr0, t1 = f1 + xr1, t2 = f2 + xr2, t3 = f3 + xr3;
        float d = at.x * LRELU(t0) + at.y * LRELU(t1)
                + at.z * LRELU(t2) + at.w * LRELU(t3);
        d += __shfl_xor(d, 1, 64);
        d += __shfl_xor(d, 2, 64);
        d += __shfl_xor(d, 4, 64);
        d += __shfl_xor(d, 8, 64);
        float p = valid ? __expf(d) : 0.f;
        a0 += p * f0; a1 += p * f1; a2 += p * f2; a3 += p * f3;
        s += p;
    }
    // combine the 4 quarter-wave edge slots
#pragma unroll
    for (int o = 16; o <= 32; o <<= 1) {
        a0 += __shfl_xor(a0, o, 64);
        a1 += __shfl_xor(a1, o, 64);
        a2 += __shfl_xor(a2, o, 64);
        a3 += __shfl_xor(a3, o, 64);
        s  += __shfl_xor(s, o, 64);
    }
    float inv = 1.f / s;
    float4 bb = *(const float4*)&bias[4 * c4];
    float4 mm = *(const float4*)&m[4 * c4];
    float4 vv = *(const float4*)&v[4 * c4];
    float4 gg = *(const float4*)&g[4 * c4];
    float4 b2 = *(const float4*)&b[4 * c4];
    float o0 = a0 * inv + bb.x, o1 = a1 * inv + bb.y;
    float o2 = a2 * inv + bb.z, o3 = a3 * inv + bb.w;
    o0 = (o0 - mm.x) * rsqrtf(vv.x + 1e-5f) * gg.x + b2.x;
    o1 = (o1 - mm.y) * rsqrtf(vv.y + 1e-5f) * gg.y + b2.y;
    o2 = (o2 - mm.z) * rsqrtf(vv.z + 1e-5f) * gg.z + b2.z;
    o3 = (o3 - mm.w) * rsqrtf(vv.w + 1e-5f) * gg.w + b2.w;
    o0 = ELU(o0); o1 = ELU(o1); o2 = ELU(o2); o3 = ELU(o3);
    float4 wc = *(const float4*)&Wc[4 * c4];
    float z = o0 * wc.x + o1 * wc.y + o2 * wc.z + o3 * wc.w;
    z += __shfl_xor(z, 1, 64);
    z += __shfl_xor(z, 2, 64);
    z += __shfl_xor(z, 4, 64);
    z += __shfl_xor(z, 8, 64);
    if (lane == 0) out[i] = 1.f / (1.f + __expf(-(z + bc[0])));
}

// ---------------- launch ----------------

extern "C" void kernel_launch(void* const* d_in, const int* in_sizes, int n_in,
                              void* d_out, int out_size, void* d_ws, size_t ws_size,
                              hipStream_t stream) {
    const float* x    = (const float*)d_in[0];
    const int*   ei   = (const int*)d_in[1];
    const float* W1l  = (const float*)d_in[2];
    const float* b1l  = (const float*)d_in[3];
    const float* W1r  = (const float*)d_in[4];
    const float* b1r  = (const float*)d_in[5];
    const float* att1 = (const float*)d_in[6];
    const float* bias1= (const float*)d_in[7];
    const float* bn1g = (const float*)d_in[8];
    const float* bn1b = (const float*)d_in[9];
    const float* bn1m = (const float*)d_in[10];
    const float* bn1v = (const float*)d_in[11];
    const float* W2l  = (const float*)d_in[12];
    const float* b2l  = (const float*)d_in[13];
    const float* W2r  = (const float*)d_in[14];
    const float* b2r  = (const float*)d_in[15];
    const float* att2 = (const float*)d_in[16];
    const float* bias2= (const float*)d_in[17];
    const float* bn2g = (const float*)d_in[18];
    const float* bn2b = (const float*)d_in[19];
    const float* bn2m = (const float*)d_in[20];
    const float* bn2v = (const float*)d_in[21];
    const float* Wc   = (const float*)d_in[22];
    const float* bc   = (const float*)d_in[23];
    float* out = (float*)d_out;

    char* ws = (char*)d_ws;
    size_t off = 0;
    auto alloc = [&](size_t bytes) {
        size_t o = off;
        off += (bytes + 255) & ~(size_t)255;
        return o;
    };
    ushort_t* xb    = (ushort_t*)(ws + alloc((size_t)(NN + 128) * 256 * 2));
    ushort_t* xlr1  = (ushort_t*)(ws + alloc((size_t)NN * 256 * 2));  // reused as xlr2
    ushort_t* h1b   = (ushort_t*)(ws + alloc((size_t)(NN + 128) * 128 * 2));
    ushort_t* Wt1   = (ushort_t*)(ws + alloc((size_t)256 * 256 * 2));
    float*    biasf1= (float*)(ws + alloc(256 * 4));
    ushort_t* Wt2   = (ushort_t*)(ws + alloc((size_t)128 * 128 * 2));
    float*    biasf2= (float*)(ws + alloc(128 * 4));
    int* deg      = (int*)(ws + alloc((size_t)NN * 4));
    int* incl     = (int*)(ws + alloc((size_t)NN * 4));
    int* rowstart = (int*)(ws + alloc((size_t)(NN + 1) * 4));
    int* totals   = (int*)(ws + alloc(64 * 4));
    int* chunkoff = (int*)(ws + alloc(64 * 4));
    int* rank     = (int*)(ws + alloc((size_t)TE * 4));
    int* ssrc     = (int*)(ws + alloc((size_t)TE * 4));
    ushort_t* xlr2 = xlr1;

    // deg = 0 (memset instead of a kernel)
    hipMemsetAsync(deg, 0, (size_t)NN * 4, stream);

    // K1: count+rank | cast x->bf16 | prep W1 | prep W2 (all independent)
    k_stage1<<<NB_K1, 256, 0, stream>>>(ei, deg, rank, x, xb,
                                        W1l, W1r, b1l, b1r, Wt1, biasf1,
                                        W2l, W2r, b2l, b2r, Wt2, biasf2);

    // scans (serial, small)
    k_scan1<<<NCHUNK, 1024, 0, stream>>>(deg, incl, totals);
    k_scan2<<<1, 64, 0, stream>>>(totals, chunkoff);
    k_scan3<<<(NN + 255) / 256, 256, 0, stream>>>(incl, deg, chunkoff, rowstart);

    // K2: GEMM layer-1 | scatter (independent; gemm blocks first)
    k_gemm1_scatter<<<NB_K2, 256, 0, stream>>>(xb, Wt1, biasf1, xlr1,
                                               ei, rank, rowstart, ssrc);

    // layer 1 fused
    k_fused1<<<(NN + 3) / 4, 256, 0, stream>>>(xlr1, rowstart, ssrc, att1, bias1,
                                               bn1g, bn1b, bn1m, bn1v, h1b);

    // layer 2 (+classifier)
    k_gemm2<<<(NN + 127) / 128, 256, 0, stream>>>(h1b, Wt2, biasf2, xlr2);
    k_fused2<<<(NN + 3) / 4, 256, 0, stream>>>(xlr2, rowstart, ssrc, att2, bias2,
                                               bn2g, bn2b, bn2m, bn2v, Wc, bc, out);
}

// Round 12
// 297.701 us; speedup vs baseline: 1.5115x; 1.0320x over previous
//
#include <hip/hip_runtime.h>
#include <hip/hip_bf16.h>
#include <cstddef>

#define NN 50000
#define EE 800000
#define TE 850000   // EE + NN self loops
#define INC 256
#define C1 128      // heads(2) * hid(64)
#define C2 64
#define NCHUNK 49   // ceil(NN/1024)

// block-range dispatch for merged kernels
#define NB_COUNT 3321   // ceil(TE/256)
#define NB_CAST  12500  // NN*INC elements / 4 per thread / 256 threads
#define NB_P1    256
#define NB_P2    128
#define NB_K1    (NB_COUNT + NB_CAST + NB_P1 + NB_P2)
#define NB_GEMM1 782    // 391*2 (128x128 tiles over 50000x256)
#define NB_K2    (NB_GEMM1 + NB_COUNT)

#define LOG2E 1.44269504088896340736f

typedef unsigned short ushort_t;
typedef short bf16x8 __attribute__((ext_vector_type(8)));
typedef float f32x4 __attribute__((ext_vector_type(4)));

__device__ inline ushort_t bf16r(float f) {  // RNE float->bf16
    unsigned u = __float_as_uint(f);
    unsigned r = (u + 0x7fffu + ((u >> 16) & 1u)) >> 16;
    return (ushort_t)r;
}
#define LOF(u) (__uint_as_float((u) << 16))           // low bf16 of packed uint
#define HIF(u) (__uint_as_float((u) & 0xffff0000u))   // high bf16 of packed uint
#define ELU(t) ((t) > 0.f ? (t) : (__expf(t) - 1.f))

// ---------------- scans (serial dependency, small) ----------------

__global__ void k_scan1(const int* __restrict__ deg, int* __restrict__ incl,
                        int* __restrict__ totals) {
    __shared__ int lds[1024];
    int t = threadIdx.x;
    int i = blockIdx.x * 1024 + t;
    int v = (i < NN) ? deg[i] : 0;
    lds[t] = v;
    __syncthreads();
    for (int off = 1; off < 1024; off <<= 1) {
        int add = (t >= off) ? lds[t - off] : 0;
        __syncthreads();
        lds[t] += add;
        __syncthreads();
    }
    if (i < NN) incl[i] = lds[t];
    if (t == 1023) totals[blockIdx.x] = lds[t];
}

// scan3 with inline chunk-offset: chunk = blockIdx.x>>2 is block-uniform,
// so a <=48-iteration scalar loop over totals replaces the scan2 kernel.
__global__ void k_scan3(const int* __restrict__ incl, const int* __restrict__ deg,
                        const int* __restrict__ totals, int* __restrict__ rowstart) {
    int i = blockIdx.x * blockDim.x + threadIdx.x;
    if (i == 0) rowstart[NN] = TE;
    if (i >= NN) return;
    int chunk = blockIdx.x >> 2;  // 256-thread blocks, 1024-wide chunks
    int coff = 0;
    for (int c = 0; c < chunk; c++) coff += totals[c];
    rowstart[i] = incl[i] - deg[i] + coff;
}

// ---------------- K1: count+rank | cast | prep_w1 | prep_w2 (independent stages) ----------------

__global__ __launch_bounds__(256) void k_stage1(
    const int* __restrict__ ei, int* __restrict__ deg, int* __restrict__ rank,
    const float* __restrict__ x, ushort_t* __restrict__ xb,
    const float* __restrict__ W1l, const float* __restrict__ W1r,
    const float* __restrict__ b1l, const float* __restrict__ b1r,
    ushort_t* __restrict__ Wt1, float* __restrict__ biasf1,
    const float* __restrict__ W2l, const float* __restrict__ W2r,
    const float* __restrict__ b2l, const float* __restrict__ b2r,
    ushort_t* __restrict__ Wt2, float* __restrict__ biasf2) {
    int b = blockIdx.x;
    int tid = threadIdx.x;
    if (b < NB_COUNT) {
        // count + per-edge rank (rank write coalesced)
        int e = b * 256 + tid;
        if (e < TE) {
            int dst = (e < EE) ? ei[EE + e] : (e - EE);
            rank[e] = atomicAdd(&deg[dst], 1);
        }
    } else if (b < NB_COUNT + NB_CAST) {
        // fp32 -> bf16 cast of x, one float4 (4 elements) per thread
        int i = (b - NB_COUNT) * 256 + tid;  // i < 3,200,000 float4's
        float4 a = ((const float4*)x)[i];
        ushort4 o;
        o.x = bf16r(a.x); o.y = bf16r(a.y); o.z = bf16r(a.z); o.w = bf16r(a.w);
        ((ushort4*)xb)[i] = o;
    } else if (b < NB_COUNT + NB_CAST + NB_P1) {
        // prep W1: Wt1[n][k], n in [0,256), K=256, HALF=128
        int n = b - NB_COUNT - NB_CAST;
        int k = tid;
        const float* W = (n < 128) ? W1l : W1r;
        int c = (n < 128) ? n : n - 128;
        Wt1[(size_t)n * 256 + k] = bf16r(W[(size_t)k * 128 + c]);
        if (n == 0) biasf1[k] = (k < 128) ? b1l[k] : b1r[k - 128];
    } else {
        // prep W2: Wt2[n][k], n in [0,128), K=128, HALF=64
        int n = b - NB_COUNT - NB_CAST - NB_P1;
        int k = tid;
        if (k < 128) {
            const float* W = (n < 64) ? W2l : W2r;
            int c = (n < 64) ? n : n - 64;
            Wt2[(size_t)n * 128 + k] = bf16r(W[(size_t)k * 64 + c]);
            if (n == 0) biasf2[k] = (k < 64) ? b2l[k] : b2r[k - 64];
        }
    }
}

// ---------------- bf16 MFMA GEMM body ----------------
// C[M,NCOL](bf16) = A[M,K](bf16) @ Bt[NCOL,K]^T + bias(fp32)
// 128x128 tile, BK=32, 256 threads, 16x16x32 MFMA; LDS rows padded to 40 bf16.

template <int K, int NCOL>
__device__ inline void gemm_body(const ushort_t* __restrict__ A,
                                 const ushort_t* __restrict__ Bt,
                                 const float* __restrict__ bias,
                                 ushort_t* __restrict__ C, int M,
                                 int bm, int bn, ushort_t* As, ushort_t* Bs) {
    int tid = threadIdx.x;
    int w = tid >> 6, l = tid & 63;
    int wm = (w & 1) * 64, wn = (w >> 1) * 64;
    int lm = l & 15, half = l >> 4;

    f32x4 zero = {0.f, 0.f, 0.f, 0.f};
    f32x4 acc[4][4];
#pragma unroll
    for (int a = 0; a < 4; a++)
#pragma unroll
        for (int b = 0; b < 4; b++) acc[a][b] = zero;

    for (int k0 = 0; k0 < K; k0 += 32) {
#pragma unroll
        for (int q = 0; q < 2; q++) {
            int seg = q * 256 + tid;
            int m = seg >> 2;
            int ko = (seg & 3) * 8;
            *(float4*)&As[m * 40 + ko] = *(const float4*)&A[(size_t)(bm + m) * K + k0 + ko];
            *(float4*)&Bs[m * 40 + ko] = *(const float4*)&Bt[(size_t)(bn + m) * K + k0 + ko];
        }
        __syncthreads();
        bf16x8 af[4], bfr[4];
#pragma unroll
        for (int mi = 0; mi < 4; mi++)
            af[mi] = *(const bf16x8*)&As[(wm + mi * 16 + lm) * 40 + half * 8];
#pragma unroll
        for (int ni = 0; ni < 4; ni++)
            bfr[ni] = *(const bf16x8*)&Bs[(wn + ni * 16 + lm) * 40 + half * 8];
#pragma unroll
        for (int mi = 0; mi < 4; mi++)
#pragma unroll
            for (int ni = 0; ni < 4; ni++)
                acc[mi][ni] = __builtin_amdgcn_mfma_f32_16x16x32_bf16(
                    af[mi], bfr[ni], acc[mi][ni], 0, 0, 0);
        __syncthreads();
    }
#pragma unroll
    for (int ni = 0; ni < 4; ni++) {
        int col = bn + wn + ni * 16 + lm;
        float bv = bias[col];
#pragma unroll
        for (int mi = 0; mi < 4; mi++) {
            int rbase = bm + wm + mi * 16 + half * 4;
#pragma unroll
            for (int r = 0; r < 4; r++) {
                int row = rbase + r;
                if (row < M) C[(size_t)row * NCOL + col] = bf16r(acc[mi][ni][r] + bv);
            }
        }
    }
}

// ---------------- K2: GEMM layer-1 | scatter (independent) ----------------

__global__ __launch_bounds__(256) void k_gemm1_scatter(
    const ushort_t* __restrict__ A, const ushort_t* __restrict__ Bt,
    const float* __restrict__ bias, ushort_t* __restrict__ C,
    const int* __restrict__ ei, const int* __restrict__ rank,
    const int* __restrict__ rowstart, int* __restrict__ ssrc) {
    __shared__ __align__(16) ushort_t As[128 * 40];
    __shared__ __align__(16) ushort_t Bs[128 * 40];
    int b = blockIdx.x;
    if (b < NB_GEMM1) {
        int bm = (b >> 1) * 128;
        int bn = (b & 1) * 128;
        gemm_body<256, 256>(A, Bt, bias, C, NN, bm, bn, As, Bs);
    } else {
        // atomic-free scatter: one independent 4B random store per edge
        int e = (b - NB_GEMM1) * 256 + threadIdx.x;
        if (e < TE) {
            int s, d;
            if (e < EE) { s = ei[e]; d = ei[EE + e]; }
            else        { s = e - EE; d = s; }
            ssrc[rowstart[d] + rank[e]] = s;
        }
    }
}

__global__ __launch_bounds__(256) void k_gemm2(
    const ushort_t* __restrict__ A, const ushort_t* __restrict__ Bt,
    const float* __restrict__ bias, ushort_t* __restrict__ C) {
    __shared__ __align__(16) ushort_t As[128 * 40];
    __shared__ __align__(16) ushort_t Bs[128 * 40];
    int bm = blockIdx.x * 128;
    gemm_body<128, 128>(A, Bt, bias, C, NN, bm, 0, As, Bs);
}

// ---------------- Fused GATv2 layer ----------------
// att*lrelu(t) = (0.6att)t + (0.4att)|t| (abs is a free VOP3 input modifier);
// att pre-scaled by log2e so p = exp2f(d) is a single v_exp_f32.

__global__ __launch_bounds__(256) void k_fused1(
    const ushort_t* __restrict__ xlr, const int* __restrict__ rowstart,
    const int* __restrict__ ssrc, const float* __restrict__ att,
    const float* __restrict__ bias,
    const float* __restrict__ g, const float* __restrict__ b,
    const float* __restrict__ m, const float* __restrict__ v,
    ushort_t* __restrict__ out) {
    int lane = threadIdx.x & 63;
    int i = blockIdx.x * 4 + (threadIdx.x >> 6);
    if (i >= NN) return;
    int hw = lane >> 5;
    int c2 = lane & 31;
    uint2 xru = *(const uint2*)&xlr[(size_t)i * 256 + 128 + 4 * c2];
    float xr0 = LOF(xru.x), xr1 = HIF(xru.x), xr2 = LOF(xru.y), xr3 = HIF(xru.y);
    float4 at = *(const float4*)&att[4 * c2];
    float4 a6 = make_float4(at.x * (0.6f * LOG2E), at.y * (0.6f * LOG2E),
                            at.z * (0.6f * LOG2E), at.w * (0.6f * LOG2E));
    float4 a4 = make_float4(at.x * (0.4f * LOG2E), at.y * (0.4f * LOG2E),
                            at.z * (0.4f * LOG2E), at.w * (0.4f * LOG2E));
    int row = rowstart[i], end = rowstart[i + 1];
    float a0 = 0.f, a1 = 0.f, a2 = 0.f, a3 = 0.f, s = 0.f;
    int j = row;
    for (; j + 8 <= end; j += 8) {
        int src[4];
        uint2 u[4];
#pragma unroll
        for (int k = 0; k < 4; k++) src[k] = ssrc[j + 2 * k + hw];
#pragma unroll
        for (int k = 0; k < 4; k++)
            u[k] = *(const uint2*)&xlr[(size_t)src[k] * 256 + 4 * c2];
        float d[4], f0[4], f1[4], f2[4], f3[4];
#pragma unroll
        for (int k = 0; k < 4; k++) {
            f0[k] = LOF(u[k].x); f1[k] = HIF(u[k].x);
            f2[k] = LOF(u[k].y); f3[k] = HIF(u[k].y);
            float t0 = f0[k] + xr0, t1 = f1[k] + xr1;
            float t2 = f2[k] + xr2, t3 = f3[k] + xr3;
            float dd = fmaf(a6.x, t0, a4.x * fabsf(t0));
            dd = fmaf(a6.y, t1, fmaf(a4.y, fabsf(t1), dd));
            dd = fmaf(a6.z, t2, fmaf(a4.z, fabsf(t2), dd));
            dd = fmaf(a6.w, t3, fmaf(a4.w, fabsf(t3), dd));
            d[k] = dd;
        }
#pragma unroll
        for (int o = 1; o <= 8; o <<= 1) {
#pragma unroll
            for (int k = 0; k < 4; k++) d[k] += __shfl_xor(d[k], o, 64);
        }
#pragma unroll
        for (int k = 0; k < 4; k++) {
            float p = exp2f(d[k]);
            a0 += p * f0[k]; a1 += p * f1[k];
            a2 += p * f2[k]; a3 += p * f3[k];
            s += p;
        }
    }
    for (; j < end; j += 2) {
        int je = j + hw;
        bool valid = je < end;
        int src = valid ? ssrc[je] : i;
        uint2 uu = *(const uint2*)&xlr[(size_t)src * 256 + 4 * c2];
        float f0 = LOF(uu.x), f1 = HIF(uu.x), f2 = LOF(uu.y), f3 = HIF(uu.y);
        float t0 = f0 + xr0, t1 = f1 + xr1, t2 = f2 + xr2, t3 = f3 + xr3;
        float dd = fmaf(a6.x, t0, a4.x * fabsf(t0));
        dd = fmaf(a6.y, t1, fmaf(a4.y, fabsf(t1), dd));
        dd = fmaf(a6.z, t2, fmaf(a4.z, fabsf(t2), dd));
        dd = fmaf(a6.w, t3, fmaf(a4.w, fabsf(t3), dd));
        dd += __shfl_xor(dd, 1, 64);
        dd += __shfl_xor(dd, 2, 64);
        dd += __shfl_xor(dd, 4, 64);
        dd += __shfl_xor(dd, 8, 64);
        float p = valid ? exp2f(dd) : 0.f;
        a0 += p * f0; a1 += p * f1; a2 += p * f2; a3 += p * f3;
        s += p;
    }
    // combine the two half-wave edge slots (channels replicated across hw)
    a0 += __shfl_xor(a0, 32, 64);
    a1 += __shfl_xor(a1, 32, 64);
    a2 += __shfl_xor(a2, 32, 64);
    a3 += __shfl_xor(a3, 32, 64);
    s  += __shfl_xor(s, 32, 64);
    if (hw == 0) {
        float inv = 1.f / s;
        float4 bb = *(const float4*)&bias[4 * c2];
        float4 mm = *(const float4*)&m[4 * c2];
        float4 vv = *(const float4*)&v[4 * c2];
        float4 gg = *(const float4*)&g[4 * c2];
        float4 b2 = *(const float4*)&b[4 * c2];
        float o0 = a0 * inv + bb.x, o1 = a1 * inv + bb.y;
        float o2 = a2 * inv + bb.z, o3 = a3 * inv + bb.w;
        o0 = (o0 - mm.x) * rsqrtf(vv.x + 1e-5f) * gg.x + b2.x;
        o1 = (o1 - mm.y) * rsqrtf(vv.y + 1e-5f) * gg.y + b2.y;
        o2 = (o2 - mm.z) * rsqrtf(vv.z + 1e-5f) * gg.z + b2.z;
        o3 = (o3 - mm.w) * rsqrtf(vv.w + 1e-5f) * gg.w + b2.w;
        o0 = ELU(o0); o1 = ELU(o1); o2 = ELU(o2); o3 = ELU(o3);
        uint2 wp;
        wp.x = (unsigned)bf16r(o0) | ((unsigned)bf16r(o1) << 16);
        wp.y = (unsigned)bf16r(o2) | ((unsigned)bf16r(o3) << 16);
        *(uint2*)&out[(size_t)i * C1 + 4 * c2] = wp;
    }
}

// Layer 2 + classifier: one wave per node; lane covers 4 of 64 channels (c4=lane&15),
// quarter-wave qw is an edge slot -> 4 edges in flight per instr.
__global__ __launch_bounds__(256) void k_fused2(
    const ushort_t* __restrict__ xlr, const int* __restrict__ rowstart,
    const int* __restrict__ ssrc, const float* __restrict__ att,
    const float* __restrict__ bias,
    const float* __restrict__ g, const float* __restrict__ b,
    const float* __restrict__ m, const float* __restrict__ v,
    const float* __restrict__ Wc, const float* __restrict__ bc,
    float* __restrict__ out) {
    int lane = threadIdx.x & 63;
    int i = blockIdx.x * 4 + (threadIdx.x >> 6);
    if (i >= NN) return;
    int qw = lane >> 4;
    int c4 = lane & 15;
    uint2 xru = *(const uint2*)&xlr[(size_t)i * 128 + 64 + 4 * c4];
    float xr0 = LOF(xru.x), xr1 = HIF(xru.x), xr2 = LOF(xru.y), xr3 = HIF(xru.y);
    float4 at = *(const float4*)&att[4 * c4];
    float4 a6 = make_float4(at.x * (0.6f * LOG2E), at.y * (0.6f * LOG2E),
                            at.z * (0.6f * LOG2E), at.w * (0.6f * LOG2E));
    float4 a4 = make_float4(at.x * (0.4f * LOG2E), at.y * (0.4f * LOG2E),
                            at.z * (0.4f * LOG2E), at.w * (0.4f * LOG2E));
    int row = rowstart[i], end = rowstart[i + 1];
    float a0 = 0.f, a1 = 0.f, a2 = 0.f, a3 = 0.f, s = 0.f;
    int j = row;
    for (; j + 8 <= end; j += 8) {
        int src[2];
        uint2 u[2];
#pragma unroll
        for (int k = 0; k < 2; k++) src[k] = ssrc[j + 4 * k + qw];
#pragma unroll
        for (int k = 0; k < 2; k++)
            u[k] = *(const uint2*)&xlr[(size_t)src[k] * 128 + 4 * c4];
        float d[2], f0[2], f1[2], f2[2], f3[2];
#pragma unroll
        for (int k = 0; k < 2; k++) {
            f0[k] = LOF(u[k].x); f1[k] = HIF(u[k].x);
            f2[k] = LOF(u[k].y); f3[k] = HIF(u[k].y);
            float t0 = f0[k] + xr0, t1 = f1[k] + xr1;
            float t2 = f2[k] + xr2, t3 = f3[k] + xr3;
            float dd = fmaf(a6.x, t0, a4.x * fabsf(t0));
            dd = fmaf(a6.y, t1, fmaf(a4.y, fabsf(t1), dd));
            dd = fmaf(a6.z, t2, fmaf(a4.z, fabsf(t2), dd));
            dd = fmaf(a6.w, t3, fmaf(a4.w, fabsf(t3), dd));
            d[k] = dd;
        }
#pragma unroll
        for (int o = 1; o <= 8; o <<= 1) {
#pragma unroll
            for (int k = 0; k < 2; k++) d[k] += __shfl_xor(d[k], o, 64);
        }
#pragma unroll
        for (int k = 0; k < 2; k++) {
            float p = exp2f(d[k]);
            a0 += p * f0[k]; a1 += p * f1[k];
            a2 += p * f2[k]; a3 += p * f3[k];
            s += p;
        }
    }
    for (; j < end; j += 4) {
        int je = j + qw;
        bool valid = je < end;
        int src = valid ? ssrc[je] : i;
        uint2 uu = *(const uint2*)&xlr[(size_t)src * 128 + 4 * c4];
        float f0 = LOF(uu.x), f1 = HIF(uu.x), f2 = LOF(uu.y), f3 = HIF(uu.y);
        float t0 = f0 + xr0, t1 = f1 + xr1, t2 = f2 + xr2, t3 = f3 + xr3;
        float dd = fmaf(a6.x, t0, a4.x * fabsf(t0));
        dd = fmaf(a6.y, t1, fmaf(a4.y, fabsf(t1), dd));
        dd = fmaf(a6.z, t2, fmaf(a4.z, fabsf(t2), dd));
        dd = fmaf(a6.w, t3, fmaf(a4.w, fabsf(t3), dd));
        dd += __shfl_xor(dd, 1, 64);
        dd += __shfl_xor(dd, 2, 64);
        dd += __shfl_xor(dd, 4, 64);
        dd += __shfl_xor(dd, 8, 64);
        float p = valid ? exp2f(dd) : 0.f;
        a0 += p * f0; a1 += p * f1; a2 += p * f2; a3 += p * f3;
        s += p;
    }
    // combine the 4 quarter-wave edge slots
#pragma unroll
    for (int o = 16; o <= 32; o <<= 1) {
        a0 += __shfl_xor(a0, o, 64);
        a1 += __shfl_xor(a1, o, 64);
        a2 += __shfl_xor(a2, o, 64);
        a3 += __shfl_xor(a3, o, 64);
        s  += __shfl_xor(s, o, 64);
    }
    float inv = 1.f / s;
    float4 bb = *(const float4*)&bias[4 * c4];
    float4 mm = *(const float4*)&m[4 * c4];
    float4 vv = *(const float4*)&v[4 * c4];
    float4 gg = *(const float4*)&g[4 * c4];
    float4 b2 = *(const float4*)&b[4 * c4];
    float o0 = a0 * inv + bb.x, o1 = a1 * inv + bb.y;
    float o2 = a2 * inv + bb.z, o3 = a3 * inv + bb.w;
    o0 = (o0 - mm.x) * rsqrtf(vv.x + 1e-5f) * gg.x + b2.x;
    o1 = (o1 - mm.y) * rsqrtf(vv.y + 1e-5f) * gg.y + b2.y;
    o2 = (o2 - mm.z) * rsqrtf(vv.z + 1e-5f) * gg.z + b2.z;
    o3 = (o3 - mm.w) * rsqrtf(vv.w + 1e-5f) * gg.w + b2.w;
    o0 = ELU(o0); o1 = ELU(o1); o2 = ELU(o2); o3 = ELU(o3);
    float4 wc = *(const float4*)&Wc[4 * c4];
    float z = o0 * wc.x + o1 * wc.y + o2 * wc.z + o3 * wc.w;
    z += __shfl_xor(z, 1, 64);
    z += __shfl_xor(z, 2, 64);
    z += __shfl_xor(z, 4, 64);
    z += __shfl_xor(z, 8, 64);
    if (lane == 0) out[i] = 1.f / (1.f + __expf(-(z + bc[0])));
}

// ---------------- launch ----------------

extern "C" void kernel_launch(void* const* d_in, const int* in_sizes, int n_in,
                              void* d_out, int out_size, void* d_ws, size_t ws_size,
                              hipStream_t stream) {
    const float* x    = (const float*)d_in[0];
    const int*   ei   = (const int*)d_in[1];
    const float* W1l  = (const float*)d_in[2];
    const float* b1l  = (const float*)d_in[3];
    const float* W1r  = (const float*)d_in[4];
    const float* b1r  = (const float*)d_in[5];
    const float* att1 = (const float*)d_in[6];
    const float* bias1= (const float*)d_in[7];
    const float* bn1g = (const float*)d_in[8];
    const float* bn1b = (const float*)d_in[9];
    const float* bn1m = (const float*)d_in[10];
    const float* bn1v = (const float*)d_in[11];
    const float* W2l  = (const float*)d_in[12];
    const float* b2l  = (const float*)d_in[13];
    const float* W2r  = (const float*)d_in[14];
    const float* b2r  = (const float*)d_in[15];
    const float* att2 = (const float*)d_in[16];
    const float* bias2= (const float*)d_in[17];
    const float* bn2g = (const float*)d_in[18];
    const float* bn2b = (const float*)d_in[19];
    const float* bn2m = (const float*)d_in[20];
    const float* bn2v = (const float*)d_in[21];
    const float* Wc   = (const float*)d_in[22];
    const float* bc   = (const float*)d_in[23];
    float* out = (float*)d_out;

    char* ws = (char*)d_ws;
    size_t off = 0;
    auto alloc = [&](size_t bytes) {
        size_t o = off;
        off += (bytes + 255) & ~(size_t)255;
        return o;
    };
    ushort_t* xb    = (ushort_t*)(ws + alloc((size_t)(NN + 128) * 256 * 2));
    ushort_t* xlr1  = (ushort_t*)(ws + alloc((size_t)NN * 256 * 2));  // reused as xlr2
    ushort_t* h1b   = (ushort_t*)(ws + alloc((size_t)(NN + 128) * 128 * 2));
    ushort_t* Wt1   = (ushort_t*)(ws + alloc((size_t)256 * 256 * 2));
    float*    biasf1= (float*)(ws + alloc(256 * 4));
    ushort_t* Wt2   = (ushort_t*)(ws + alloc((size_t)128 * 128 * 2));
    float*    biasf2= (float*)(ws + alloc(128 * 4));
    int* deg      = (int*)(ws + alloc((size_t)NN * 4));
    int* incl     = (int*)(ws + alloc((size_t)NN * 4));
    int* rowstart = (int*)(ws + alloc((size_t)(NN + 1) * 4));
    int* totals   = (int*)(ws + alloc(64 * 4));
    int* rank     = (int*)(ws + alloc((size_t)TE * 4));
    int* ssrc     = (int*)(ws + alloc((size_t)TE * 4));
    ushort_t* xlr2 = xlr1;

    // deg = 0 (memset instead of a kernel)
    hipMemsetAsync(deg, 0, (size_t)NN * 4, stream);

    // K1: count+rank | cast x->bf16 | prep W1 | prep W2 (all independent)
    k_stage1<<<NB_K1, 256, 0, stream>>>(ei, deg, rank, x, xb,
                                        W1l, W1r, b1l, b1r, Wt1, biasf1,
                                        W2l, W2r, b2l, b2r, Wt2, biasf2);

    // scans (serial, small; scan2 folded into scan3)
    k_scan1<<<NCHUNK, 1024, 0, stream>>>(deg, incl, totals);
    k_scan3<<<(NN + 255) / 256, 256, 0, stream>>>(incl, deg, totals, rowstart);

    // K2: GEMM layer-1 | scatter (independent; gemm blocks first)
    k_gemm1_scatter<<<NB_K2, 256, 0, stream>>>(xb, Wt1, biasf1, xlr1,
                                               ei, rank, rowstart, ssrc);

    // layer 1 fused
    k_fused1<<<(NN + 3) / 4, 256, 0, stream>>>(xlr1, rowstart, ssrc, att1, bias1,
                                               bn1g, bn1b, bn1m, bn1v, h1b);

    // layer 2 (+classifier)
    k_gemm2<<<(NN + 127) / 128, 256, 0, stream>>>(h1b, Wt2, biasf2, xlr2);
    k_fused2<<<(NN + 3) / 4, 256, 0, stream>>>(xlr2, rowstart, ssrc, att2, bias2,
                                               bn2g, bn2b, bn2m, bn2v, Wc, bc, out);
}